// Round 2
// baseline (1139.380 us; speedup 1.0000x reference)
//
#include <hip/hip_runtime.h>
#include <hip/hip_bf16.h>
#include <stdint.h>
#include <stddef.h>

typedef __hip_bfloat16 bf16;
typedef __attribute__((ext_vector_type(8))) short bhalf8;
typedef __attribute__((ext_vector_type(4))) float floatx4;

static __device__ __forceinline__ float b2f(bf16 v) { return __bfloat162float(v); }
static __device__ __forceinline__ bf16  f2b(float v) { return __float2bfloat16(v); }

// dtype-agnostic scalar load: flag==1 -> fp32 data, flag==0 -> bf16 data
static __device__ __forceinline__ float loadf(const void* p, size_t i, int f32) {
    return f32 ? ((const float*)p)[i] : b2f(((const bf16*)p)[i]);
}

// -------------------------------------------------------------------------
// Detect input dtype regime from raw bits of W1 (values ~ N(0, 0.05)).
// bf16 shorts have exponent in ~[0x60,0x90]; fp32-as-shorts have random
// exponent bits in even lanes. Count out-of-range exponents over 256 shorts.
__global__ void detect_k(const void* w1raw, int* flag)
{
    if (threadIdx.x == 0 && blockIdx.x == 0) {
        const unsigned short* s = (const unsigned short*)w1raw;
        int bad = 0;
        for (int i = 0; i < 256; i++) {
            int e = (s[i] >> 7) & 0xFF;
            if (e > 0x85 || (e != 0 && e < 0x60)) bad++;
        }
        *flag = (bad > 16) ? 1 : 0;
    }
}

// convert (or pass through) to bf16
__global__ __launch_bounds__(256) void cvt_k(const void* __restrict__ src,
                                             bf16* __restrict__ dst, int n,
                                             const int* __restrict__ flag)
{
    const int f = *flag;
    int i = blockIdx.x * 256 + threadIdx.x;
    if (i < n) dst[i] = f ? f2b(((const float*)src)[i]) : ((const bf16*)src)[i];
}

// -------------------------------------------------------------------------
// transpose: in (R x C) row-major (raw dtype) -> out (C x R) row-major, bf16
__global__ __launch_bounds__(256) void transpose_k(const void* __restrict__ in,
                                                   bf16* __restrict__ out,
                                                   int R, int C,
                                                   const int* __restrict__ flag)
{
    __shared__ bf16 tile[32][33];
    const int f = *flag;
    const int tx = threadIdx.x & 31;
    const int ty = threadIdx.x >> 5;            // 0..7
    const int c0 = blockIdx.x * 32;
    const int r0 = blockIdx.y * 32;
    #pragma unroll
    for (int yy = ty; yy < 32; yy += 8)
        tile[yy][tx] = f2b(loadf(in, (size_t)(r0 + yy) * C + c0 + tx, f));
    __syncthreads();
    #pragma unroll
    for (int yy = ty; yy < 32; yy += 8)
        out[(size_t)(c0 + yy) * R + r0 + tx] = tile[tx][yy];
}

// -------------------------------------------------------------------------
// C (M x N) = A (M x K) @ B (K x N), B given transposed: Bt (N x K) row-major.
// bf16 in/out, fp32 accum. 128x128x32 tile, 4 waves (2x2), mfma 16x16x32 bf16.
__global__ __launch_bounds__(256) void gemm_bt(const bf16* __restrict__ A,
                                               const bf16* __restrict__ Bt,
                                               bf16* __restrict__ C,
                                               int M, int N, int K)
{
    __shared__ __align__(16) short sA[128][32];
    __shared__ __align__(16) short sB[128][32];
    const int tid  = threadIdx.x;
    const int bx   = blockIdx.x, by = blockIdx.y;
    const int wave = tid >> 6, lane = tid & 63;
    const int wm   = wave >> 1, wn = wave & 1;
    const int lrow = lane & 15, quad = lane >> 4;

    floatx4 acc[4][4];
    #pragma unroll
    for (int i = 0; i < 4; i++)
        #pragma unroll
        for (int j = 0; j < 4; j++)
            acc[i][j] = (floatx4){0.f, 0.f, 0.f, 0.f};

    const int srow = tid >> 1;          // 0..127
    const int scol = (tid & 1) * 16;    // 0 or 16 (shorts)
    const bf16* Ap = A  + (size_t)(by * 128 + srow) * K + scol;
    const bf16* Bp = Bt + (size_t)(bx * 128 + srow) * K + scol;

    for (int k0 = 0; k0 < K; k0 += 32) {
        int4 a0 = *(const int4*)(Ap + k0);
        int4 a1 = *(const int4*)(Ap + k0 + 8);
        int4 b0 = *(const int4*)(Bp + k0);
        int4 b1 = *(const int4*)(Bp + k0 + 8);
        __syncthreads();
        *(int4*)&sA[srow][scol]     = a0;
        *(int4*)&sA[srow][scol + 8] = a1;
        *(int4*)&sB[srow][scol]     = b0;
        *(int4*)&sB[srow][scol + 8] = b1;
        __syncthreads();
        bhalf8 af[4], bfr[4];
        #pragma unroll
        for (int t = 0; t < 4; t++) af[t]  = *(const bhalf8*)&sA[wm * 64 + t * 16 + lrow][quad * 8];
        #pragma unroll
        for (int t = 0; t < 4; t++) bfr[t] = *(const bhalf8*)&sB[wn * 64 + t * 16 + lrow][quad * 8];
        #pragma unroll
        for (int tm = 0; tm < 4; tm++)
            #pragma unroll
            for (int tn = 0; tn < 4; tn++)
                acc[tm][tn] = __builtin_amdgcn_mfma_f32_16x16x32_bf16(af[tm], bfr[tn], acc[tm][tn], 0, 0, 0);
    }

    // C/D layout (m89-verified): col = lane&15, row = quad*4 + r
    #pragma unroll
    for (int tm = 0; tm < 4; tm++) {
        #pragma unroll
        for (int tn = 0; tn < 4; tn++) {
            const int col = bx * 128 + wn * 64 + tn * 16 + lrow;
            #pragma unroll
            for (int r = 0; r < 4; r++) {
                const int row = by * 128 + wm * 64 + tm * 16 + quad * 4 + r;
                C[(size_t)row * N + col] = f2b(acc[tm][tn][r]);
            }
        }
    }
}

// -------------------------------------------------------------------------
template <bool MAX>
static __device__ __forceinline__ float block_reduce(float v, volatile float* s4)
{
    #pragma unroll
    for (int off = 32; off; off >>= 1) {
        float o = __shfl_down(v, off, 64);
        v = MAX ? fmaxf(v, o) : v + o;
    }
    __syncthreads();                       // protect scratch from previous use
    if ((threadIdx.x & 63) == 0) s4[threadIdx.x >> 6] = v;
    __syncthreads();
    return MAX ? fmaxf(fmaxf(s4[0], s4[1]), fmaxf(s4[2], s4[3]))
               : (s4[0] + s4[1]) + (s4[2] + s4[3]);
}

// s_src_t/s_tgt_t layout: [(b*8+h)*1024 + n], fp32
__global__ __launch_bounds__(256) void compute_s(const bf16* __restrict__ p,
                                                 const void* __restrict__ a_src,
                                                 const void* __restrict__ a_tgt,
                                                 float* __restrict__ s_src_t,
                                                 float* __restrict__ s_tgt_t,
                                                 const int* __restrict__ flag)
{
    __shared__ float scratch[4];
    const int f32 = *flag;
    const int bn = blockIdx.x;            // 0..4095
    const int tid = threadIdx.x;          // = f
    const int b = bn >> 10, n = bn & 1023;
    for (int h = 0; h < 8; h++) {
        float pv = b2f(p[(size_t)bn * 2048 + h * 256 + tid]);
        float ps = pv * loadf(a_src, h * 256 + tid, f32);
        float pt = pv * loadf(a_tgt, h * 256 + tid, f32);
        float ssum = block_reduce<false>(ps, scratch);
        float tsum = block_reduce<false>(pt, scratch);
        if (tid == 0) {
            s_src_t[(b * 8 + h) * 1024 + n] = ssum;
            s_tgt_t[(b * 8 + h) * 1024 + n] = tsum;
        }
    }
}

// -------------------------------------------------------------------------
// One block per (b, h, 8-row i-tile). Dense softmax over j (N=1024) + weighted
// aggregation of p + skip/bias/activation epilogue.
// LAYER==1: x2 = elu(attn + sk + b1)  (bf16 out)
// LAYER==2: atomicAdd(out2, (attn + sk) / 8)  (fp32, head-mean)
template <int LAYER>
__global__ __launch_bounds__(256) void attn_k(const bf16* __restrict__ p,
                                              const bf16* __restrict__ sk,
                                              const void* __restrict__ bias,
                                              const float* __restrict__ s_src_t,
                                              const float* __restrict__ s_tgt_t,
                                              const void* __restrict__ mask,
                                              bf16* __restrict__ x2,
                                              float* __restrict__ out2,
                                              const int* __restrict__ flag)
{
    __shared__ __align__(16) float w[8][1024];   // softmax numerators
    __shared__ float stgt[1024];
    __shared__ float ssrc[8];
    __shared__ float invl[8];
    __shared__ float scratch[4];

    const int f32 = *flag;
    const int blk = blockIdx.x;
    const int bh = blk >> 7, itile = blk & 127;
    const int b = bh >> 3, h = bh & 7;
    const int tid = threadIdx.x;

    #pragma unroll
    for (int q = 0; q < 4; q++) stgt[q * 256 + tid] = s_tgt_t[bh * 1024 + q * 256 + tid];
    if (tid < 8) ssrc[tid] = s_src_t[bh * 1024 + itile * 8 + tid];
    __syncthreads();

    // ---- phase 1: softmax weights for 8 rows ----
    for (int r = 0; r < 8; r++) {
        const int i = itile * 8 + r;
        const size_t moff = ((size_t)b * 1024 + i) * 1024;
        const float ssr = ssrc[r];
        float sc[4];
        float mloc = -3e38f;
        #pragma unroll
        for (int q = 0; q < 4; q++) {
            const int j = q * 256 + tid;
            float x = ssr + stgt[j];
            x = (x > 0.f) ? x : 0.2f * x;      // leaky_relu(0.2)
            x += loadf(mask, moff + j, f32);   // additive mask
            sc[q] = x;
            mloc = fmaxf(mloc, x);
        }
        const float m = block_reduce<true>(mloc, scratch);
        float lloc = 0.f;
        #pragma unroll
        for (int q = 0; q < 4; q++) {
            float e = __expf(sc[q] - m);
            w[r][q * 256 + tid] = e;
            lloc += e;
        }
        const float l = block_reduce<false>(lloc, scratch);
        if (tid == 0) invl[r] = 1.0f / l;
    }
    __syncthreads();

    // ---- phase 2: out[r][f] = sum_j w[r][j] * p[b,j,h,f], f = tid ----
    float acc[8] = {0.f, 0.f, 0.f, 0.f, 0.f, 0.f, 0.f, 0.f};
    const bf16* pb = p + (size_t)b * 1024 * 2048 + h * 256 + tid;
    for (int j0 = 0; j0 < 1024; j0 += 4) {
        float4 wv[8];
        #pragma unroll
        for (int r = 0; r < 8; r++) wv[r] = *(const float4*)&w[r][j0];
        #pragma unroll
        for (int dj = 0; dj < 4; dj++) {
            const float pv = b2f(pb[(size_t)(j0 + dj) * 2048]);
            #pragma unroll
            for (int r = 0; r < 8; r++) {
                const float wval = (dj == 0) ? wv[r].x : (dj == 1) ? wv[r].y
                                 : (dj == 2) ? wv[r].z : wv[r].w;
                acc[r] = fmaf(wval, pv, acc[r]);
            }
        }
    }

    // ---- epilogue ----
    #pragma unroll
    for (int r = 0; r < 8; r++) {
        const int i = itile * 8 + r;
        const size_t off = ((size_t)b * 1024 + i) * 2048 + h * 256 + tid;
        float v = acc[r] * invl[r] + b2f(sk[off]);
        if (LAYER == 1) {
            v += loadf(bias, h * 256 + tid, f32);
            v = (v > 0.f) ? v : expm1f(v);     // ELU
            x2[off] = f2b(v);
        } else {
            atomicAdd(&out2[((size_t)b * 1024 + i) * 256 + tid], v * 0.125f);
        }
    }
}

// -------------------------------------------------------------------------
__global__ void zero_f(float* __restrict__ p, int n)
{
    int idx = blockIdx.x * blockDim.x + threadIdx.x;
    if (idx < n) p[idx] = 0.f;
}

// partial node-mean: g[b*256+f] += sum over 64 nodes
__global__ __launch_bounds__(256) void pool_k(const float* __restrict__ out2,
                                              float* __restrict__ g)
{
    const int b = blockIdx.x, chunk = blockIdx.y, f = threadIdx.x;
    float s = 0.f;
    for (int i = 0; i < 64; i++)
        s += out2[((size_t)b * 1024 + chunk * 64 + i) * 256 + f];
    atomicAdd(&g[b * 256 + f], s);
}

__global__ void classify_k(const float* __restrict__ g,
                           const void* __restrict__ b2,
                           const void* __restrict__ Wc,
                           const void* __restrict__ bc,
                           void* __restrict__ out,
                           const int* __restrict__ flag)
{
    const int f32 = *flag;
    const int b = blockIdx.x, c = threadIdx.x;
    if (c < 10) {
        float acc = loadf(bc, c, f32);
        for (int f = 0; f < 256; f++) {
            float gv = g[b * 256 + f] * (1.0f / 1024.0f) + loadf(b2, f, f32);
            acc += gv * loadf(Wc, f * 10 + c, f32);
        }
        if (f32) ((float*)out)[b * 10 + c] = acc;
        else     ((bf16*)out)[b * 10 + c] = f2b(acc);
    }
}

// -------------------------------------------------------------------------
extern "C" void kernel_launch(void* const* d_in, const int* in_sizes, int n_in,
                              void* d_out, int out_size, void* d_ws, size_t ws_size,
                              hipStream_t stream)
{
    (void)in_sizes; (void)n_in; (void)out_size; (void)ws_size;
    const void* feat   = d_in[0];
    // d_in[1] eigvects: unused by forward
    const void* mask   = d_in[2];
    const void* W1     = d_in[3];
    const void* a_src1 = d_in[4];
    const void* a_tgt1 = d_in[5];
    const void* skip1  = d_in[6];
    const void* b1     = d_in[7];
    const void* W2     = d_in[8];
    const void* a_src2 = d_in[9];
    const void* a_tgt2 = d_in[10];
    const void* skip2  = d_in[11];
    const void* b2v    = d_in[12];
    const void* Wc     = d_in[13];
    const void* bc     = d_in[14];

    char* ws = (char*)d_ws;
    size_t off = 0;
    auto alloc = [&](size_t bytes) -> void* {
        void* p = ws + off;
        off += (bytes + 255) & ~(size_t)255;
        return p;
    };
    int*   flag = (int*)alloc(256);
    bf16*  featc= (bf16*)alloc(4096ull * 256 * 2);
    bf16*  W1t  = (bf16*)alloc(2048ull * 256 * 2);
    bf16*  S1t  = (bf16*)alloc(2048ull * 256 * 2);
    bf16*  W2t  = (bf16*)alloc(2048ull * 2048 * 2);
    bf16*  S2t  = (bf16*)alloc(2048ull * 2048 * 2);
    bf16*  p1   = (bf16*)alloc(4096ull * 2048 * 2);
    bf16*  sk1  = (bf16*)alloc(4096ull * 2048 * 2);
    bf16*  x2   = (bf16*)alloc(4096ull * 2048 * 2);
    float* ss1  = (float*)alloc(32ull * 1024 * 4);
    float* st1  = (float*)alloc(32ull * 1024 * 4);
    float* ss2  = (float*)alloc(32ull * 1024 * 4);
    float* st2  = (float*)alloc(32ull * 1024 * 4);
    float* out2 = (float*)alloc(4096ull * 256 * 4);
    float* g    = (float*)alloc(4ull * 256 * 4);
    bf16* p2  = p1;   // reuse: p1 dead after attn layer 1
    bf16* sk2 = sk1;  // reuse

    // dtype detection + input normalization to bf16
    detect_k<<<1, 64, 0, stream>>>(W1, flag);
    cvt_k<<<4096, 256, 0, stream>>>(feat, featc, 4096 * 256, flag);

    // weight transposes (Bt layout for the GEMM), flag-aware loads
    transpose_k<<<dim3(64, 8),  256, 0, stream>>>(W1,    W1t, 256, 2048, flag);
    transpose_k<<<dim3(64, 8),  256, 0, stream>>>(skip1, S1t, 256, 2048, flag);
    transpose_k<<<dim3(64, 64), 256, 0, stream>>>(W2,    W2t, 2048, 2048, flag);
    transpose_k<<<dim3(64, 64), 256, 0, stream>>>(skip2, S2t, 2048, 2048, flag);

    // ---- layer 1 ----
    gemm_bt<<<dim3(16, 32), 256, 0, stream>>>(featc, W1t, p1,  4096, 2048, 256);
    gemm_bt<<<dim3(16, 32), 256, 0, stream>>>(featc, S1t, sk1, 4096, 2048, 256);
    compute_s<<<4096, 256, 0, stream>>>(p1, a_src1, a_tgt1, ss1, st1, flag);
    attn_k<1><<<4096, 256, 0, stream>>>(p1, sk1, b1, ss1, st1, mask, x2, nullptr, flag);

    // ---- layer 2 ----
    gemm_bt<<<dim3(16, 32), 256, 0, stream>>>(x2, W2t, p2,  4096, 2048, 2048);
    gemm_bt<<<dim3(16, 32), 256, 0, stream>>>(x2, S2t, sk2, 4096, 2048, 2048);
    compute_s<<<4096, 256, 0, stream>>>(p2, a_src2, a_tgt2, ss2, st2, flag);
    zero_f<<<4096, 256, 0, stream>>>(out2, 4096 * 256);
    zero_f<<<4,    256, 0, stream>>>(g, 1024);
    attn_k<2><<<4096, 256, 0, stream>>>(p2, sk2, nullptr, ss2, st2, mask, nullptr, out2, flag);

    // ---- pool + classify ----
    pool_k<<<dim3(4, 16), 256, 0, stream>>>(out2, g);
    classify_k<<<4, 64, 0, stream>>>(g, b2v, Wc, bc, d_out, flag);
}

// Round 3
// 600.610 us; speedup vs baseline: 1.8970x; 1.8970x over previous
//
#include <hip/hip_runtime.h>
#include <hip/hip_bf16.h>
#include <stdint.h>
#include <stddef.h>

typedef __hip_bfloat16 bf16;
typedef __attribute__((ext_vector_type(8))) short bhalf8;
typedef __attribute__((ext_vector_type(4))) float floatx4;

static __device__ __forceinline__ float b2f(bf16 v) { return __bfloat162float(v); }
static __device__ __forceinline__ bf16  f2b(float v) { return __float2bfloat16(v); }

// dtype-agnostic scalar load: flag==1 -> fp32 data, flag==0 -> bf16 data
static __device__ __forceinline__ float loadf(const void* p, size_t i, int f32) {
    return f32 ? ((const float*)p)[i] : b2f(((const bf16*)p)[i]);
}

// -------------------------------------------------------------------------
// Detect input dtype regime from raw bits of W1 (values ~ N(0, 0.05)).
__global__ void detect_k(const void* w1raw, int* flag)
{
    if (threadIdx.x == 0 && blockIdx.x == 0) {
        const unsigned short* s = (const unsigned short*)w1raw;
        int bad = 0;
        for (int i = 0; i < 256; i++) {
            int e = (s[i] >> 7) & 0xFF;
            if (e > 0x85 || (e != 0 && e < 0x60)) bad++;
        }
        *flag = (bad > 16) ? 1 : 0;
    }
}

// convert (or pass through) to bf16
__global__ __launch_bounds__(256) void cvt_k(const void* __restrict__ src,
                                             bf16* __restrict__ dst, int n,
                                             const int* __restrict__ flag)
{
    const int f = *flag;
    int i = blockIdx.x * 256 + threadIdx.x;
    if (i < n) dst[i] = f ? f2b(((const float*)src)[i]) : ((const bf16*)src)[i];
}

// -------------------------------------------------------------------------
// transpose: in (R x C) row-major (raw dtype) -> out (C x R) row-major, bf16
__global__ __launch_bounds__(256) void transpose_k(const void* __restrict__ in,
                                                   bf16* __restrict__ out,
                                                   int R, int C,
                                                   const int* __restrict__ flag)
{
    __shared__ bf16 tile[32][33];
    const int f = *flag;
    const int tx = threadIdx.x & 31;
    const int ty = threadIdx.x >> 5;            // 0..7
    const int c0 = blockIdx.x * 32;
    const int r0 = blockIdx.y * 32;
    #pragma unroll
    for (int yy = ty; yy < 32; yy += 8)
        tile[yy][tx] = f2b(loadf(in, (size_t)(r0 + yy) * C + c0 + tx, f));
    __syncthreads();
    #pragma unroll
    for (int yy = ty; yy < 32; yy += 8)
        out[(size_t)(c0 + yy) * R + r0 + tx] = tile[tx][yy];
}

// batched bf16 transpose: per b, in (1024 x 2048) -> out (2048 x 1024)
__global__ __launch_bounds__(256) void transpose_p(const bf16* __restrict__ in,
                                                   bf16* __restrict__ out)
{
    __shared__ bf16 tile[32][33];
    const int bz = blockIdx.z;
    const int tx = threadIdx.x & 31;
    const int ty = threadIdx.x >> 5;
    const int c0 = blockIdx.x * 32;
    const int r0 = blockIdx.y * 32;
    const bf16* ib = in + (size_t)bz * 1024 * 2048;
    bf16* ob = out + (size_t)bz * 1024 * 2048;
    #pragma unroll
    for (int yy = ty; yy < 32; yy += 8)
        tile[yy][tx] = ib[(size_t)(r0 + yy) * 2048 + c0 + tx];
    __syncthreads();
    #pragma unroll
    for (int yy = ty; yy < 32; yy += 8)
        ob[(size_t)(c0 + yy) * 1024 + r0 + tx] = tile[tx][yy];
}

// -------------------------------------------------------------------------
// C (M x N) = A (M x K) @ B (K x N), B given transposed: Bt (N x K) row-major.
// bf16 in/out, fp32 accum. 128x128x32 tile, 4 waves (2x2), mfma 16x16x32 bf16.
__global__ __launch_bounds__(256) void gemm_bt(const bf16* __restrict__ A,
                                               const bf16* __restrict__ Bt,
                                               bf16* __restrict__ C,
                                               int M, int N, int K)
{
    __shared__ __align__(16) short sA[128][32];
    __shared__ __align__(16) short sB[128][32];
    const int tid  = threadIdx.x;
    const int bx   = blockIdx.x, by = blockIdx.y;
    const int wave = tid >> 6, lane = tid & 63;
    const int wm   = wave >> 1, wn = wave & 1;
    const int lrow = lane & 15, quad = lane >> 4;

    floatx4 acc[4][4];
    #pragma unroll
    for (int i = 0; i < 4; i++)
        #pragma unroll
        for (int j = 0; j < 4; j++)
            acc[i][j] = (floatx4){0.f, 0.f, 0.f, 0.f};

    const int srow = tid >> 1;          // 0..127
    const int scol = (tid & 1) * 16;    // 0 or 16 (shorts)
    const bf16* Ap = A  + (size_t)(by * 128 + srow) * K + scol;
    const bf16* Bp = Bt + (size_t)(bx * 128 + srow) * K + scol;

    for (int k0 = 0; k0 < K; k0 += 32) {
        int4 a0 = *(const int4*)(Ap + k0);
        int4 a1 = *(const int4*)(Ap + k0 + 8);
        int4 b0 = *(const int4*)(Bp + k0);
        int4 b1 = *(const int4*)(Bp + k0 + 8);
        __syncthreads();
        *(int4*)&sA[srow][scol]     = a0;
        *(int4*)&sA[srow][scol + 8] = a1;
        *(int4*)&sB[srow][scol]     = b0;
        *(int4*)&sB[srow][scol + 8] = b1;
        __syncthreads();
        bhalf8 af[4], bfr[4];
        #pragma unroll
        for (int t = 0; t < 4; t++) af[t]  = *(const bhalf8*)&sA[wm * 64 + t * 16 + lrow][quad * 8];
        #pragma unroll
        for (int t = 0; t < 4; t++) bfr[t] = *(const bhalf8*)&sB[wn * 64 + t * 16 + lrow][quad * 8];
        #pragma unroll
        for (int tm = 0; tm < 4; tm++)
            #pragma unroll
            for (int tn = 0; tn < 4; tn++)
                acc[tm][tn] = __builtin_amdgcn_mfma_f32_16x16x32_bf16(af[tm], bfr[tn], acc[tm][tn], 0, 0, 0);
    }

    // C/D layout (m89-verified): col = lane&15, row = quad*4 + r
    #pragma unroll
    for (int tm = 0; tm < 4; tm++) {
        #pragma unroll
        for (int tn = 0; tn < 4; tn++) {
            const int col = bx * 128 + wn * 64 + tn * 16 + lrow;
            #pragma unroll
            for (int r = 0; r < 4; r++) {
                const int row = by * 128 + wm * 64 + tm * 16 + quad * 4 + r;
                C[(size_t)row * N + col] = f2b(acc[tm][tn][r]);
            }
        }
    }
}

// -------------------------------------------------------------------------
template <bool MAX>
static __device__ __forceinline__ float block_reduce(float v, volatile float* s4)
{
    #pragma unroll
    for (int off = 32; off; off >>= 1) {
        float o = __shfl_down(v, off, 64);
        v = MAX ? fmaxf(v, o) : v + o;
    }
    __syncthreads();                       // protect scratch from previous use
    if ((threadIdx.x & 63) == 0) s4[threadIdx.x >> 6] = v;
    __syncthreads();
    return MAX ? fmaxf(fmaxf(s4[0], s4[1]), fmaxf(s4[2], s4[3]))
               : (s4[0] + s4[1]) + (s4[2] + s4[3]);
}

// s_src_t/s_tgt_t layout: [(b*8+h)*1024 + n], fp32
__global__ __launch_bounds__(256) void compute_s(const bf16* __restrict__ p,
                                                 const void* __restrict__ a_src,
                                                 const void* __restrict__ a_tgt,
                                                 float* __restrict__ s_src_t,
                                                 float* __restrict__ s_tgt_t,
                                                 const int* __restrict__ flag)
{
    __shared__ float scratch[4];
    const int f32 = *flag;
    const int bn = blockIdx.x;            // 0..4095
    const int tid = threadIdx.x;          // = f
    const int b = bn >> 10, n = bn & 1023;
    for (int h = 0; h < 8; h++) {
        float pv = b2f(p[(size_t)bn * 2048 + h * 256 + tid]);
        float ps = pv * loadf(a_src, h * 256 + tid, f32);
        float pt = pv * loadf(a_tgt, h * 256 + tid, f32);
        float ssum = block_reduce<false>(ps, scratch);
        float tsum = block_reduce<false>(pt, scratch);
        if (tid == 0) {
            s_src_t[(b * 8 + h) * 1024 + n] = ssum;
            s_tgt_t[(b * 8 + h) * 1024 + n] = tsum;
        }
    }
}

// -------------------------------------------------------------------------
// Softmax numerators (bf16) + per-row inverse denominator.
// wbuf[bh][i][j] = exp(score - rowmax); invl[bh*1024+i] = 1/sum_j
__global__ __launch_bounds__(256) void softmax_k(const float* __restrict__ s_src_t,
                                                 const float* __restrict__ s_tgt_t,
                                                 const void* __restrict__ mask,
                                                 bf16* __restrict__ wbuf,
                                                 float* __restrict__ invl,
                                                 const int* __restrict__ flag)
{
    __shared__ float stgt[1024];
    __shared__ float ssrc[8];
    __shared__ float scratch[4];

    const int f32 = *flag;
    const int blk = blockIdx.x;
    const int bh = blk >> 7, itile = blk & 127;
    const int b = bh >> 3;
    const int tid = threadIdx.x;

    #pragma unroll
    for (int q = 0; q < 4; q++) stgt[q * 256 + tid] = s_tgt_t[bh * 1024 + q * 256 + tid];
    if (tid < 8) ssrc[tid] = s_src_t[bh * 1024 + itile * 8 + tid];
    __syncthreads();

    bf16* wb = wbuf + ((size_t)bh << 20);      // bh * 1024*1024

    for (int r = 0; r < 8; r++) {
        const int i = itile * 8 + r;
        const size_t moff = ((size_t)b * 1024 + i) * 1024;
        const float ssr = ssrc[r];
        float sc[4];
        float mloc = -3e38f;
        #pragma unroll
        for (int q = 0; q < 4; q++) {
            const int j = q * 256 + tid;
            float x = ssr + stgt[j];
            x = (x > 0.f) ? x : 0.2f * x;      // leaky_relu(0.2)
            x += loadf(mask, moff + j, f32);   // additive mask
            sc[q] = x;
            mloc = fmaxf(mloc, x);
        }
        const float m = block_reduce<true>(mloc, scratch);
        float lloc = 0.f;
        #pragma unroll
        for (int q = 0; q < 4; q++) {
            float e = __expf(sc[q] - m);
            wb[(size_t)i * 1024 + q * 256 + tid] = f2b(e);
            lloc += e;
        }
        const float l = block_reduce<false>(lloc, scratch);
        if (tid == 0) invl[bh * 1024 + i] = 1.0f / l;
    }
}

// -------------------------------------------------------------------------
// Attention aggregation as batched MFMA GEMM, per (b,h):
//   out(1024 x 256) = w(1024 x 1024) @ p_h(1024 x 256)
// A = wbuf[bh] (M=1024,K=1024), Bt = pT[bh] (N=256 rows, K=1024).
// Epilogue: multiply by invl[row]; LAYER 1: +sk+bias, ELU -> x2 (bf16);
// LAYER 2: raw fp32 per-head store to o2f (head-mean happens in pool2_k).
template <int LAYER>
__global__ __launch_bounds__(256) void attn_gemm(const bf16* __restrict__ wbuf,
                                                 const bf16* __restrict__ pT,
                                                 const float* __restrict__ invl,
                                                 const bf16* __restrict__ sk,
                                                 const void* __restrict__ bias,
                                                 bf16* __restrict__ x2,
                                                 float* __restrict__ o2f,
                                                 const int* __restrict__ flag)
{
    __shared__ __align__(16) short sA[128][32];
    __shared__ __align__(16) short sB[128][32];
    const int tid  = threadIdx.x;
    const int bx   = blockIdx.x, by = blockIdx.y, bh = blockIdx.z;
    const int b = bh >> 3, h = bh & 7;
    const int wave = tid >> 6, lane = tid & 63;
    const int wm   = wave >> 1, wn = wave & 1;
    const int lrow = lane & 15, quad = lane >> 4;
    const int f32  = *flag;

    const bf16* A  = wbuf + ((size_t)bh << 20);       // 1024x1024
    const bf16* Bt = pT   + ((size_t)bh << 18);       // 256x1024

    floatx4 acc[4][4];
    #pragma unroll
    for (int i = 0; i < 4; i++)
        #pragma unroll
        for (int j = 0; j < 4; j++)
            acc[i][j] = (floatx4){0.f, 0.f, 0.f, 0.f};

    const int srow = tid >> 1;
    const int scol = (tid & 1) * 16;
    const bf16* Ap = A  + (size_t)(by * 128 + srow) * 1024 + scol;
    const bf16* Bp = Bt + (size_t)(bx * 128 + srow) * 1024 + scol;

    for (int k0 = 0; k0 < 1024; k0 += 32) {
        int4 a0 = *(const int4*)(Ap + k0);
        int4 a1 = *(const int4*)(Ap + k0 + 8);
        int4 b0 = *(const int4*)(Bp + k0);
        int4 b1 = *(const int4*)(Bp + k0 + 8);
        __syncthreads();
        *(int4*)&sA[srow][scol]     = a0;
        *(int4*)&sA[srow][scol + 8] = a1;
        *(int4*)&sB[srow][scol]     = b0;
        *(int4*)&sB[srow][scol + 8] = b1;
        __syncthreads();
        bhalf8 af[4], bfr[4];
        #pragma unroll
        for (int t = 0; t < 4; t++) af[t]  = *(const bhalf8*)&sA[wm * 64 + t * 16 + lrow][quad * 8];
        #pragma unroll
        for (int t = 0; t < 4; t++) bfr[t] = *(const bhalf8*)&sB[wn * 64 + t * 16 + lrow][quad * 8];
        #pragma unroll
        for (int tm = 0; tm < 4; tm++)
            #pragma unroll
            for (int tn = 0; tn < 4; tn++)
                acc[tm][tn] = __builtin_amdgcn_mfma_f32_16x16x32_bf16(af[tm], bfr[tn], acc[tm][tn], 0, 0, 0);
    }

    #pragma unroll
    for (int tm = 0; tm < 4; tm++) {
        #pragma unroll
        for (int r = 0; r < 4; r++) {
            const int row = by * 128 + wm * 64 + tm * 16 + quad * 4 + r;
            const float il = invl[bh * 1024 + row];
            #pragma unroll
            for (int tn = 0; tn < 4; tn++) {
                const int col = bx * 128 + wn * 64 + tn * 16 + lrow;   // 0..255
                float v = acc[tm][tn][r] * il;
                if (LAYER == 1) {
                    const int hf = h * 256 + col;
                    const size_t idx = ((size_t)(b * 1024 + row)) * 2048 + hf;
                    v += b2f(sk[idx]) + loadf(bias, hf, f32);
                    v = (v > 0.f) ? v : expm1f(v);     // ELU
                    x2[idx] = f2b(v);
                } else {
                    o2f[((size_t)(bh * 1024 + row)) * 256 + col] = v;
                }
            }
        }
    }
}

// -------------------------------------------------------------------------
__global__ void zero_f(float* __restrict__ p, int n)
{
    int idx = blockIdx.x * blockDim.x + threadIdx.x;
    if (idx < n) p[idx] = 0.f;
}

// fused head-mean + skip + node-pool partial:
// g[b,f] += sum_{i in chunk} (1/8) sum_h (o2f[bh,i,f] + sk2[b,i,h*256+f])
__global__ __launch_bounds__(256) void pool2_k(const float* __restrict__ o2f,
                                               const bf16* __restrict__ sk2,
                                               float* __restrict__ g)
{
    const int b = blockIdx.x, chunk = blockIdx.y, f = threadIdx.x;
    float s = 0.f;
    for (int ii = 0; ii < 64; ii++) {
        const int i = chunk * 64 + ii;
        #pragma unroll
        for (int h = 0; h < 8; h++) {
            s += o2f[((size_t)((b * 8 + h) * 1024 + i)) * 256 + f]
               + b2f(sk2[((size_t)(b * 1024 + i)) * 2048 + h * 256 + f]);
        }
    }
    atomicAdd(&g[b * 256 + f], s * 0.125f);
}

__global__ void classify_k(const float* __restrict__ g,
                           const void* __restrict__ b2,
                           const void* __restrict__ Wc,
                           const void* __restrict__ bc,
                           void* __restrict__ out,
                           const int* __restrict__ flag)
{
    const int f32 = *flag;
    const int b = blockIdx.x, c = threadIdx.x;
    if (c < 10) {
        float acc = loadf(bc, c, f32);
        for (int f = 0; f < 256; f++) {
            float gv = g[b * 256 + f] * (1.0f / 1024.0f) + loadf(b2, f, f32);
            acc += gv * loadf(Wc, f * 10 + c, f32);
        }
        if (f32) ((float*)out)[b * 10 + c] = acc;
        else     ((bf16*)out)[b * 10 + c] = f2b(acc);
    }
}

// -------------------------------------------------------------------------
extern "C" void kernel_launch(void* const* d_in, const int* in_sizes, int n_in,
                              void* d_out, int out_size, void* d_ws, size_t ws_size,
                              hipStream_t stream)
{
    (void)in_sizes; (void)n_in; (void)out_size; (void)ws_size;
    const void* feat   = d_in[0];
    // d_in[1] eigvects: unused by forward
    const void* mask   = d_in[2];
    const void* W1     = d_in[3];
    const void* a_src1 = d_in[4];
    const void* a_tgt1 = d_in[5];
    const void* skip1  = d_in[6];
    const void* b1     = d_in[7];
    const void* W2     = d_in[8];
    const void* a_src2 = d_in[9];
    const void* a_tgt2 = d_in[10];
    const void* skip2  = d_in[11];
    const void* b2v    = d_in[12];
    const void* Wc     = d_in[13];
    const void* bc     = d_in[14];

    char* ws = (char*)d_ws;
    size_t off = 0;
    auto alloc = [&](size_t bytes) -> void* {
        void* p = ws + off;
        off += (bytes + 255) & ~(size_t)255;
        return p;
    };
    int*   flag = (int*)alloc(256);
    bf16*  featc= (bf16*)alloc(4096ull * 256 * 2);
    bf16*  W1t  = (bf16*)alloc(2048ull * 256 * 2);
    bf16*  S1t  = (bf16*)alloc(2048ull * 256 * 2);
    bf16*  W2t  = (bf16*)alloc(2048ull * 2048 * 2);
    bf16*  S2t  = (bf16*)alloc(2048ull * 2048 * 2);
    bf16*  p1   = (bf16*)alloc(4096ull * 2048 * 2);
    bf16*  sk1  = (bf16*)alloc(4096ull * 2048 * 2);
    bf16*  x2   = (bf16*)alloc(4096ull * 2048 * 2);
    bf16*  pT   = (bf16*)alloc(4096ull * 2048 * 2);
    bf16*  wbuf = (bf16*)alloc(32ull * 1024 * 1024 * 2);
    float* invl = (float*)alloc(32ull * 1024 * 4);
    float* ss1  = (float*)alloc(32ull * 1024 * 4);
    float* st1  = (float*)alloc(32ull * 1024 * 4);
    float* ss2  = (float*)alloc(32ull * 1024 * 4);
    float* st2  = (float*)alloc(32ull * 1024 * 4);
    float* o2f  = (float*)alloc(32ull * 1024 * 256 * 4);
    float* g    = (float*)alloc(4ull * 256 * 4);
    bf16* p2  = p1;   // reuse: p1 dead after transpose_p of layer 1
    bf16* sk2 = sk1;  // reuse

    // dtype detection + input normalization to bf16
    detect_k<<<1, 64, 0, stream>>>(W1, flag);
    cvt_k<<<4096, 256, 0, stream>>>(feat, featc, 4096 * 256, flag);

    // weight transposes (Bt layout for the GEMM), flag-aware loads
    transpose_k<<<dim3(64, 8),  256, 0, stream>>>(W1,    W1t, 256, 2048, flag);
    transpose_k<<<dim3(64, 8),  256, 0, stream>>>(skip1, S1t, 256, 2048, flag);
    transpose_k<<<dim3(64, 64), 256, 0, stream>>>(W2,    W2t, 2048, 2048, flag);
    transpose_k<<<dim3(64, 64), 256, 0, stream>>>(skip2, S2t, 2048, 2048, flag);

    // ---- layer 1 ----
    gemm_bt<<<dim3(16, 32), 256, 0, stream>>>(featc, W1t, p1,  4096, 2048, 256);
    gemm_bt<<<dim3(16, 32), 256, 0, stream>>>(featc, S1t, sk1, 4096, 2048, 256);
    compute_s<<<4096, 256, 0, stream>>>(p1, a_src1, a_tgt1, ss1, st1, flag);
    softmax_k<<<4096, 256, 0, stream>>>(ss1, st1, mask, wbuf, invl, flag);
    transpose_p<<<dim3(64, 32, 4), 256, 0, stream>>>(p1, pT);
    attn_gemm<1><<<dim3(2, 8, 32), 256, 0, stream>>>(wbuf, pT, invl, sk1, b1, x2, nullptr, flag);

    // ---- layer 2 ----
    gemm_bt<<<dim3(16, 32), 256, 0, stream>>>(x2, W2t, p2,  4096, 2048, 2048);
    gemm_bt<<<dim3(16, 32), 256, 0, stream>>>(x2, S2t, sk2, 4096, 2048, 2048);
    compute_s<<<4096, 256, 0, stream>>>(p2, a_src2, a_tgt2, ss2, st2, flag);
    softmax_k<<<4096, 256, 0, stream>>>(ss2, st2, mask, wbuf, invl, flag);
    transpose_p<<<dim3(64, 32, 4), 256, 0, stream>>>(p2, pT);
    attn_gemm<2><<<dim3(2, 8, 32), 256, 0, stream>>>(wbuf, pT, invl, nullptr, nullptr, nullptr, o2f, flag);

    // ---- pool + classify ----
    zero_f<<<4, 256, 0, stream>>>(g, 1024);
    pool2_k<<<dim3(4, 16), 256, 0, stream>>>(o2f, sk2, g);
    classify_k<<<4, 64, 0, stream>>>(g, b2v, Wc, bc, d_out, flag);
}

// Round 4
// 563.451 us; speedup vs baseline: 2.0221x; 1.0659x over previous
//
#include <hip/hip_runtime.h>
#include <hip/hip_bf16.h>
#include <stdint.h>
#include <stddef.h>

typedef __hip_bfloat16 bf16;
typedef __attribute__((ext_vector_type(8))) short bhalf8;
typedef __attribute__((ext_vector_type(4))) float floatx4;

static __device__ __forceinline__ float b2f(bf16 v) { return __bfloat162float(v); }
static __device__ __forceinline__ bf16  f2b(float v) { return __float2bfloat16(v); }

// dtype-agnostic scalar load: flag==1 -> fp32 data, flag==0 -> bf16 data
static __device__ __forceinline__ float loadf(const void* p, size_t i, int f32) {
    return f32 ? ((const float*)p)[i] : b2f(((const bf16*)p)[i]);
}

// async global->LDS, 16B per lane. LDS dest must be wave-uniform base + lane*16.
static __device__ __forceinline__ void gl_lds16(const void* g, void* l) {
    __builtin_amdgcn_global_load_lds(
        (const __attribute__((address_space(1))) void*)g,
        (__attribute__((address_space(3))) void*)l, 16, 0, 0);
}

// -------------------------------------------------------------------------
// Detect input dtype regime from raw bits of W1 (values ~ N(0, 0.05)).
__global__ void detect_k(const void* w1raw, int* flag)
{
    if (threadIdx.x == 0 && blockIdx.x == 0) {
        const unsigned short* s = (const unsigned short*)w1raw;
        int bad = 0;
        for (int i = 0; i < 256; i++) {
            int e = (s[i] >> 7) & 0xFF;
            if (e > 0x85 || (e != 0 && e < 0x60)) bad++;
        }
        *flag = (bad > 16) ? 1 : 0;
    }
}

// convert (or pass through) to bf16
__global__ __launch_bounds__(256) void cvt_k(const void* __restrict__ src,
                                             bf16* __restrict__ dst, int n,
                                             const int* __restrict__ flag)
{
    const int f = *flag;
    int i = blockIdx.x * 256 + threadIdx.x;
    if (i < n) dst[i] = f ? f2b(((const float*)src)[i]) : ((const bf16*)src)[i];
}

// -------------------------------------------------------------------------
// transpose: in (R x C) row-major (raw dtype) -> out (C x R) row-major, bf16
__global__ __launch_bounds__(256) void transpose_k(const void* __restrict__ in,
                                                   bf16* __restrict__ out,
                                                   int R, int C,
                                                   const int* __restrict__ flag)
{
    __shared__ bf16 tile[32][33];
    const int f = *flag;
    const int tx = threadIdx.x & 31;
    const int ty = threadIdx.x >> 5;            // 0..7
    const int c0 = blockIdx.x * 32;
    const int r0 = blockIdx.y * 32;
    #pragma unroll
    for (int yy = ty; yy < 32; yy += 8)
        tile[yy][tx] = f2b(loadf(in, (size_t)(r0 + yy) * C + c0 + tx, f));
    __syncthreads();
    #pragma unroll
    for (int yy = ty; yy < 32; yy += 8)
        out[(size_t)(c0 + yy) * R + r0 + tx] = tile[tx][yy];
}

// batched bf16 transpose: per b, in (1024 x 2048) -> out (2048 x 1024)
__global__ __launch_bounds__(256) void transpose_p(const bf16* __restrict__ in,
                                                   bf16* __restrict__ out)
{
    __shared__ bf16 tile[32][33];
    const int bz = blockIdx.z;
    const int tx = threadIdx.x & 31;
    const int ty = threadIdx.x >> 5;
    const int c0 = blockIdx.x * 32;
    const int r0 = blockIdx.y * 32;
    const bf16* ib = in + (size_t)bz * 1024 * 2048;
    bf16* ob = out + (size_t)bz * 1024 * 2048;
    #pragma unroll
    for (int yy = ty; yy < 32; yy += 8)
        tile[yy][tx] = ib[(size_t)(r0 + yy) * 2048 + c0 + tx];
    __syncthreads();
    #pragma unroll
    for (int yy = ty; yy < 32; yy += 8)
        ob[(size_t)(c0 + yy) * 1024 + r0 + tx] = tile[tx][yy];
}

// -------------------------------------------------------------------------
// Paired GEMM: C0 = A@B0, C1 = A@B1 (blockIdx.z selects), Bt row-major (N x K).
// 128x128x32 tile, 4 waves, mfma 16x16x32 bf16, global_load_lds staging (m97).
__global__ __launch_bounds__(256) void gemm_bt2(const bf16* __restrict__ A,
                                                const bf16* __restrict__ Bt0,
                                                const bf16* __restrict__ Bt1,
                                                bf16* __restrict__ C0,
                                                bf16* __restrict__ C1,
                                                int M, int N, int K)
{
    __shared__ __align__(16) short sA[128][32];
    __shared__ __align__(16) short sB[128][32];
    const int tid  = threadIdx.x;
    const int bx   = blockIdx.x, by = blockIdx.y;
    const bf16* Bt = blockIdx.z ? Bt1 : Bt0;
    bf16* C        = blockIdx.z ? C1  : C0;
    const int wave = tid >> 6, lane = tid & 63;
    const int wm   = wave >> 1, wn = wave & 1;
    const int lrow = lane & 15, quad = lane >> 4;

    floatx4 acc[4][4];
    #pragma unroll
    for (int i = 0; i < 4; i++)
        #pragma unroll
        for (int j = 0; j < 4; j++)
            acc[i][j] = (floatx4){0.f, 0.f, 0.f, 0.f};

    // global_load_lds staging: wave w covers 32 rows (2 calls x 16 rows).
    const int srow = wave * 32 + (lane >> 2);      // + 0 / +16
    const int scol = (lane & 3) * 8;               // shorts
    const bf16* gA0 = A  + (size_t)(by * 128 + srow) * K + scol;
    const bf16* gA1 = gA0 + (size_t)16 * K;
    const bf16* gB0 = Bt + (size_t)(bx * 128 + srow) * K + scol;
    const bf16* gB1 = gB0 + (size_t)16 * K;
    char* lA0 = (char*)&sA[0][0] + wave * 2048 + lane * 16;
    char* lA1 = lA0 + 1024;
    char* lB0 = (char*)&sB[0][0] + wave * 2048 + lane * 16;
    char* lB1 = lB0 + 1024;

    for (int k0 = 0; k0 < K; k0 += 32) {
        __syncthreads();                 // LDS consumers of prev iter done
        gl_lds16(gA0 + k0, lA0);
        gl_lds16(gA1 + k0, lA1);
        gl_lds16(gB0 + k0, lB0);
        gl_lds16(gB1 + k0, lB1);
        __syncthreads();                 // drain global_load_lds (vmcnt)
        bhalf8 af[4], bfr[4];
        #pragma unroll
        for (int t = 0; t < 4; t++) af[t]  = *(const bhalf8*)&sA[wm * 64 + t * 16 + lrow][quad * 8];
        #pragma unroll
        for (int t = 0; t < 4; t++) bfr[t] = *(const bhalf8*)&sB[wn * 64 + t * 16 + lrow][quad * 8];
        #pragma unroll
        for (int tm = 0; tm < 4; tm++)
            #pragma unroll
            for (int tn = 0; tn < 4; tn++)
                acc[tm][tn] = __builtin_amdgcn_mfma_f32_16x16x32_bf16(af[tm], bfr[tn], acc[tm][tn], 0, 0, 0);
    }

    // C/D layout (m89-verified): col = lane&15, row = quad*4 + r
    #pragma unroll
    for (int tm = 0; tm < 4; tm++) {
        #pragma unroll
        for (int tn = 0; tn < 4; tn++) {
            const int col = bx * 128 + wn * 64 + tn * 16 + lrow;
            #pragma unroll
            for (int r = 0; r < 4; r++) {
                const int row = by * 128 + wm * 64 + tm * 16 + quad * 4 + r;
                C[(size_t)row * N + col] = f2b(acc[tm][tn][r]);
            }
        }
    }
}

// -------------------------------------------------------------------------
template <bool MAX>
static __device__ __forceinline__ float block_reduce(float v, volatile float* s4)
{
    #pragma unroll
    for (int off = 32; off; off >>= 1) {
        float o = __shfl_down(v, off, 64);
        v = MAX ? fmaxf(v, o) : v + o;
    }
    __syncthreads();
    if ((threadIdx.x & 63) == 0) s4[threadIdx.x >> 6] = v;
    __syncthreads();
    return MAX ? fmaxf(fmaxf(s4[0], s4[1]), fmaxf(s4[2], s4[3]))
               : (s4[0] + s4[1]) + (s4[2] + s4[3]);
}

// -------------------------------------------------------------------------
// s_src/s_tgt from TRANSPOSED p: thread = node n, serial loop over f.
// pT[bh][f][n]; outputs [(bh)*1024 + n], fp32.
__global__ __launch_bounds__(256) void compute_s_T(const bf16* __restrict__ pT,
                                                   const void* __restrict__ a_src,
                                                   const void* __restrict__ a_tgt,
                                                   float* __restrict__ s_src_t,
                                                   float* __restrict__ s_tgt_t,
                                                   const int* __restrict__ flag)
{
    __shared__ float sas[256], sat[256];
    const int f32 = *flag;
    const int bh = blockIdx.x;             // 0..31
    const int h = bh & 7;
    const int n = blockIdx.y * 256 + threadIdx.x;
    sas[threadIdx.x] = loadf(a_src, h * 256 + threadIdx.x, f32);
    sat[threadIdx.x] = loadf(a_tgt, h * 256 + threadIdx.x, f32);
    __syncthreads();
    const bf16* base = pT + ((size_t)bh << 18) + n;
    float ss = 0.f, st = 0.f;
    #pragma unroll 8
    for (int f = 0; f < 256; f++) {
        float pv = b2f(base[(size_t)f << 10]);
        ss = fmaf(pv, sas[f], ss);
        st = fmaf(pv, sat[f], st);
    }
    s_src_t[bh * 1024 + n] = ss;
    s_tgt_t[bh * 1024 + n] = st;
}

// -------------------------------------------------------------------------
// Softmax numerators (bf16) + per-row inverse denominator.
__global__ __launch_bounds__(256) void softmax_k(const float* __restrict__ s_src_t,
                                                 const float* __restrict__ s_tgt_t,
                                                 const void* __restrict__ mask,
                                                 bf16* __restrict__ wbuf,
                                                 float* __restrict__ invl,
                                                 const int* __restrict__ flag)
{
    __shared__ float stgt[1024];
    __shared__ float ssrc[8];
    __shared__ float scratch[4];

    const int f32 = *flag;
    const int blk = blockIdx.x;
    const int bh = blk >> 7, itile = blk & 127;
    const int b = bh >> 3;
    const int tid = threadIdx.x;

    #pragma unroll
    for (int q = 0; q < 4; q++) stgt[q * 256 + tid] = s_tgt_t[bh * 1024 + q * 256 + tid];
    if (tid < 8) ssrc[tid] = s_src_t[bh * 1024 + itile * 8 + tid];
    __syncthreads();

    bf16* wb = wbuf + ((size_t)bh << 20);

    for (int r = 0; r < 8; r++) {
        const int i = itile * 8 + r;
        const size_t moff = ((size_t)b * 1024 + i) * 1024;
        const float ssr = ssrc[r];
        float sc[4];
        float mloc = -3e38f;
        #pragma unroll
        for (int q = 0; q < 4; q++) {
            const int j = q * 256 + tid;
            float x = ssr + stgt[j];
            x = (x > 0.f) ? x : 0.2f * x;      // leaky_relu(0.2)
            x += loadf(mask, moff + j, f32);   // additive mask
            sc[q] = x;
            mloc = fmaxf(mloc, x);
        }
        const float m = block_reduce<true>(mloc, scratch);
        float lloc = 0.f;
        #pragma unroll
        for (int q = 0; q < 4; q++) {
            float e = __expf(sc[q] - m);
            wb[(size_t)i * 1024 + q * 256 + tid] = f2b(e);
            lloc += e;
        }
        const float l = block_reduce<false>(lloc, scratch);
        if (tid == 0) invl[bh * 1024 + i] = 1.0f / l;
    }
}

// -------------------------------------------------------------------------
// Attention aggregation per (b,h): out(1024x256) = w(1024x1024) @ p_h(1024x256).
// A = wbuf[bh], Bt = pT[bh] (256 x 1024). global_load_lds staging.
template <int LAYER>
__global__ __launch_bounds__(256) void attn_gemm(const bf16* __restrict__ wbuf,
                                                 const bf16* __restrict__ pT,
                                                 const float* __restrict__ invl,
                                                 const bf16* __restrict__ sk,
                                                 const void* __restrict__ bias,
                                                 bf16* __restrict__ x2,
                                                 float* __restrict__ o2f,
                                                 const int* __restrict__ flag)
{
    __shared__ __align__(16) short sA[128][32];
    __shared__ __align__(16) short sB[128][32];
    const int tid  = threadIdx.x;
    const int bx   = blockIdx.x, by = blockIdx.y, bh = blockIdx.z;
    const int b = bh >> 3, h = bh & 7;
    const int wave = tid >> 6, lane = tid & 63;
    const int wm   = wave >> 1, wn = wave & 1;
    const int lrow = lane & 15, quad = lane >> 4;
    const int f32  = *flag;

    const bf16* A  = wbuf + ((size_t)bh << 20);       // 1024x1024
    const bf16* Bt = pT   + ((size_t)bh << 18);       // 256x1024

    floatx4 acc[4][4];
    #pragma unroll
    for (int i = 0; i < 4; i++)
        #pragma unroll
        for (int j = 0; j < 4; j++)
            acc[i][j] = (floatx4){0.f, 0.f, 0.f, 0.f};

    const int srow = wave * 32 + (lane >> 2);
    const int scol = (lane & 3) * 8;
    const bf16* gA0 = A  + (size_t)(by * 128 + srow) * 1024 + scol;
    const bf16* gA1 = gA0 + (size_t)16 * 1024;
    const bf16* gB0 = Bt + (size_t)(bx * 128 + srow) * 1024 + scol;
    const bf16* gB1 = gB0 + (size_t)16 * 1024;
    char* lA0 = (char*)&sA[0][0] + wave * 2048 + lane * 16;
    char* lA1 = lA0 + 1024;
    char* lB0 = (char*)&sB[0][0] + wave * 2048 + lane * 16;
    char* lB1 = lB0 + 1024;

    for (int k0 = 0; k0 < 1024; k0 += 32) {
        __syncthreads();
        gl_lds16(gA0 + k0, lA0);
        gl_lds16(gA1 + k0, lA1);
        gl_lds16(gB0 + k0, lB0);
        gl_lds16(gB1 + k0, lB1);
        __syncthreads();
        bhalf8 af[4], bfr[4];
        #pragma unroll
        for (int t = 0; t < 4; t++) af[t]  = *(const bhalf8*)&sA[wm * 64 + t * 16 + lrow][quad * 8];
        #pragma unroll
        for (int t = 0; t < 4; t++) bfr[t] = *(const bhalf8*)&sB[wn * 64 + t * 16 + lrow][quad * 8];
        #pragma unroll
        for (int tm = 0; tm < 4; tm++)
            #pragma unroll
            for (int tn = 0; tn < 4; tn++)
                acc[tm][tn] = __builtin_amdgcn_mfma_f32_16x16x32_bf16(af[tm], bfr[tn], acc[tm][tn], 0, 0, 0);
    }

    #pragma unroll
    for (int tm = 0; tm < 4; tm++) {
        #pragma unroll
        for (int r = 0; r < 4; r++) {
            const int row = by * 128 + wm * 64 + tm * 16 + quad * 4 + r;
            const float il = invl[bh * 1024 + row];
            #pragma unroll
            for (int tn = 0; tn < 4; tn++) {
                const int col = bx * 128 + wn * 64 + tn * 16 + lrow;   // 0..255
                float v = acc[tm][tn][r] * il;
                if (LAYER == 1) {
                    const int hf = h * 256 + col;
                    const size_t idx = ((size_t)(b * 1024 + row)) * 2048 + hf;
                    v += b2f(sk[idx]) + loadf(bias, hf, f32);
                    v = (v > 0.f) ? v : expm1f(v);     // ELU
                    x2[idx] = f2b(v);
                } else {
                    o2f[((size_t)(bh * 1024 + row)) * 256 + col] = v;
                }
            }
        }
    }
}

// -------------------------------------------------------------------------
__global__ void zero_f(float* __restrict__ p, int n)
{
    int idx = blockIdx.x * blockDim.x + threadIdx.x;
    if (idx < n) p[idx] = 0.f;
}

// fused head-mean + skip + node-pool partial
__global__ __launch_bounds__(256) void pool2_k(const float* __restrict__ o2f,
                                               const bf16* __restrict__ sk2,
                                               float* __restrict__ g)
{
    const int b = blockIdx.x, chunk = blockIdx.y, f = threadIdx.x;
    float s = 0.f;
    for (int ii = 0; ii < 64; ii++) {
        const int i = chunk * 64 + ii;
        #pragma unroll
        for (int h = 0; h < 8; h++) {
            s += o2f[((size_t)((b * 8 + h) * 1024 + i)) * 256 + f]
               + b2f(sk2[((size_t)(b * 1024 + i)) * 2048 + h * 256 + f]);
        }
    }
    atomicAdd(&g[b * 256 + f], s * 0.125f);
}

__global__ void classify_k(const float* __restrict__ g,
                           const void* __restrict__ b2,
                           const void* __restrict__ Wc,
                           const void* __restrict__ bc,
                           void* __restrict__ out,
                           const int* __restrict__ flag)
{
    const int f32 = *flag;
    const int b = blockIdx.x, c = threadIdx.x;
    if (c < 10) {
        float acc = loadf(bc, c, f32);
        for (int f = 0; f < 256; f++) {
            float gv = g[b * 256 + f] * (1.0f / 1024.0f) + loadf(b2, f, f32);
            acc += gv * loadf(Wc, f * 10 + c, f32);
        }
        if (f32) ((float*)out)[b * 10 + c] = acc;
        else     ((bf16*)out)[b * 10 + c] = f2b(acc);
    }
}

// -------------------------------------------------------------------------
extern "C" void kernel_launch(void* const* d_in, const int* in_sizes, int n_in,
                              void* d_out, int out_size, void* d_ws, size_t ws_size,
                              hipStream_t stream)
{
    (void)in_sizes; (void)n_in; (void)out_size; (void)ws_size;
    const void* feat   = d_in[0];
    const void* mask   = d_in[2];
    const void* W1     = d_in[3];
    const void* a_src1 = d_in[4];
    const void* a_tgt1 = d_in[5];
    const void* skip1  = d_in[6];
    const void* b1     = d_in[7];
    const void* W2     = d_in[8];
    const void* a_src2 = d_in[9];
    const void* a_tgt2 = d_in[10];
    const void* skip2  = d_in[11];
    const void* b2v    = d_in[12];
    const void* Wc     = d_in[13];
    const void* bc     = d_in[14];

    char* ws = (char*)d_ws;
    size_t off = 0;
    auto alloc = [&](size_t bytes) -> void* {
        void* p = ws + off;
        off += (bytes + 255) & ~(size_t)255;
        return p;
    };
    int*   flag = (int*)alloc(256);
    bf16*  featc= (bf16*)alloc(4096ull * 256 * 2);
    bf16*  W1t  = (bf16*)alloc(2048ull * 256 * 2);
    bf16*  S1t  = (bf16*)alloc(2048ull * 256 * 2);
    bf16*  W2t  = (bf16*)alloc(2048ull * 2048 * 2);
    bf16*  S2t  = (bf16*)alloc(2048ull * 2048 * 2);
    bf16*  p1   = (bf16*)alloc(4096ull * 2048 * 2);
    bf16*  sk1  = (bf16*)alloc(4096ull * 2048 * 2);
    bf16*  x2   = (bf16*)alloc(4096ull * 2048 * 2);
    bf16*  pT   = (bf16*)alloc(4096ull * 2048 * 2);
    bf16*  wbuf = (bf16*)alloc(32ull * 1024 * 1024 * 2);
    float* invl = (float*)alloc(32ull * 1024 * 4);
    float* ss1  = (float*)alloc(32ull * 1024 * 4);
    float* st1  = (float*)alloc(32ull * 1024 * 4);
    float* ss2  = (float*)alloc(32ull * 1024 * 4);
    float* st2  = (float*)alloc(32ull * 1024 * 4);
    float* o2f  = (float*)alloc(32ull * 1024 * 256 * 4);
    float* g    = (float*)alloc(4ull * 256 * 4);
    bf16* p2  = p1;   // reuse: p1 dead after transpose_p (compute_s reads pT)
    bf16* sk2 = sk1;  // reuse: sk1 consumed by attn_gemm<1> before layer-2 gemm

    detect_k<<<1, 64, 0, stream>>>(W1, flag);
    cvt_k<<<4096, 256, 0, stream>>>(feat, featc, 4096 * 256, flag);

    transpose_k<<<dim3(64, 8),  256, 0, stream>>>(W1,    W1t, 256, 2048, flag);
    transpose_k<<<dim3(64, 8),  256, 0, stream>>>(skip1, S1t, 256, 2048, flag);
    transpose_k<<<dim3(64, 64), 256, 0, stream>>>(W2,    W2t, 2048, 2048, flag);
    transpose_k<<<dim3(64, 64), 256, 0, stream>>>(skip2, S2t, 2048, 2048, flag);

    // ---- layer 1 ----
    gemm_bt2<<<dim3(16, 32, 2), 256, 0, stream>>>(featc, W1t, S1t, p1, sk1, 4096, 2048, 256);
    transpose_p<<<dim3(64, 32, 4), 256, 0, stream>>>(p1, pT);
    compute_s_T<<<dim3(32, 4), 256, 0, stream>>>(pT, a_src1, a_tgt1, ss1, st1, flag);
    softmax_k<<<4096, 256, 0, stream>>>(ss1, st1, mask, wbuf, invl, flag);
    attn_gemm<1><<<dim3(2, 8, 32), 256, 0, stream>>>(wbuf, pT, invl, sk1, b1, x2, nullptr, flag);

    // ---- layer 2 ----
    gemm_bt2<<<dim3(16, 32, 2), 256, 0, stream>>>(x2, W2t, S2t, p2, sk2, 4096, 2048, 2048);
    transpose_p<<<dim3(64, 32, 4), 256, 0, stream>>>(p2, pT);
    compute_s_T<<<dim3(32, 4), 256, 0, stream>>>(pT, a_src2, a_tgt2, ss2, st2, flag);
    softmax_k<<<4096, 256, 0, stream>>>(ss2, st2, mask, wbuf, invl, flag);
    attn_gemm<2><<<dim3(2, 8, 32), 256, 0, stream>>>(wbuf, pT, invl, nullptr, nullptr, nullptr, o2f, flag);

    // ---- pool + classify ----
    zero_f<<<4, 256, 0, stream>>>(g, 1024);
    pool2_k<<<dim3(4, 16), 256, 0, stream>>>(o2f, sk2, g);
    classify_k<<<4, 64, 0, stream>>>(g, b2v, Wc, bc, d_out, flag);
}

// Round 5
// 483.517 us; speedup vs baseline: 2.3564x; 1.1653x over previous
//
#include <hip/hip_runtime.h>
#include <hip/hip_bf16.h>
#include <stdint.h>
#include <stddef.h>

typedef __hip_bfloat16 bf16;
typedef __attribute__((ext_vector_type(8))) short bhalf8;
typedef __attribute__((ext_vector_type(4))) float floatx4;

static __device__ __forceinline__ float b2f(bf16 v) { return __bfloat162float(v); }
static __device__ __forceinline__ bf16  f2b(float v) { return __float2bfloat16(v); }

// dtype-agnostic scalar load: flag==1 -> fp32 data, flag==0 -> bf16 data
static __device__ __forceinline__ float loadf(const void* p, size_t i, int f32) {
    return f32 ? ((const float*)p)[i] : b2f(((const bf16*)p)[i]);
}

// async global->LDS, 16B per lane. LDS dest must be wave-uniform base + lane*16.
static __device__ __forceinline__ void gl_lds16(const void* g, void* l) {
    __builtin_amdgcn_global_load_lds(
        (const __attribute__((address_space(1))) void*)g,
        (__attribute__((address_space(3))) void*)l, 16, 0, 0);
}

// -------------------------------------------------------------------------
__global__ void detect_k(const void* w1raw, int* flag)
{
    if (threadIdx.x == 0 && blockIdx.x == 0) {
        const unsigned short* s = (const unsigned short*)w1raw;
        int bad = 0;
        for (int i = 0; i < 256; i++) {
            int e = (s[i] >> 7) & 0xFF;
            if (e > 0x85 || (e != 0 && e < 0x60)) bad++;
        }
        *flag = (bad > 16) ? 1 : 0;
    }
}

__global__ __launch_bounds__(256) void cvt_k(const void* __restrict__ src,
                                             bf16* __restrict__ dst, int n,
                                             const int* __restrict__ flag)
{
    const int f = *flag;
    int i = blockIdx.x * 256 + threadIdx.x;
    if (i < n) dst[i] = f ? f2b(((const float*)src)[i]) : ((const bf16*)src)[i];
}

// -------------------------------------------------------------------------
// transpose: in (R x C) row-major (raw dtype) -> out (C x R) row-major, bf16
__global__ __launch_bounds__(256) void transpose_k(const void* __restrict__ in,
                                                   bf16* __restrict__ out,
                                                   int R, int C,
                                                   const int* __restrict__ flag)
{
    __shared__ bf16 tile[32][33];
    const int f = *flag;
    const int tx = threadIdx.x & 31;
    const int ty = threadIdx.x >> 5;
    const int c0 = blockIdx.x * 32;
    const int r0 = blockIdx.y * 32;
    #pragma unroll
    for (int yy = ty; yy < 32; yy += 8)
        tile[yy][tx] = f2b(loadf(in, (size_t)(r0 + yy) * C + c0 + tx, f));
    __syncthreads();
    #pragma unroll
    for (int yy = ty; yy < 32; yy += 8)
        out[(size_t)(c0 + yy) * R + r0 + tx] = tile[tx][yy];
}

// batched bf16 transpose: per b, in (1024 x 2048) -> out (2048 x 1024)
__global__ __launch_bounds__(256) void transpose_p(const bf16* __restrict__ in,
                                                   bf16* __restrict__ out)
{
    __shared__ bf16 tile[32][33];
    const int bz = blockIdx.z;
    const int tx = threadIdx.x & 31;
    const int ty = threadIdx.x >> 5;
    const int c0 = blockIdx.x * 32;
    const int r0 = blockIdx.y * 32;
    const bf16* ib = in + (size_t)bz * 1024 * 2048;
    bf16* ob = out + (size_t)bz * 1024 * 2048;
    #pragma unroll
    for (int yy = ty; yy < 32; yy += 8)
        tile[yy][tx] = ib[(size_t)(r0 + yy) * 2048 + c0 + tx];
    __syncthreads();
    #pragma unroll
    for (int yy = ty; yy < 32; yy += 8)
        ob[(size_t)(c0 + yy) * 1024 + r0 + tx] = tile[tx][yy];
}

// -------------------------------------------------------------------------
// Paired GEMM: C = A@B[z], Bt row-major (N x K). 128x128x32 tile, 4 waves,
// mfma 16x16x32 bf16, global_load_lds width-16 staging (m97 structure).
__global__ __launch_bounds__(256) void gemm_bt2(const bf16* __restrict__ A,
                                                const bf16* __restrict__ Bt0,
                                                const bf16* __restrict__ Bt1,
                                                bf16* __restrict__ C0,
                                                bf16* __restrict__ C1,
                                                int M, int N, int K)
{
    __shared__ __align__(16) short sA[128][32];
    __shared__ __align__(16) short sB[128][32];
    const int tid  = threadIdx.x;
    const int bx   = blockIdx.x, by = blockIdx.y;
    const bf16* Bt = blockIdx.z ? Bt1 : Bt0;
    bf16* C        = blockIdx.z ? C1  : C0;
    const int wave = tid >> 6, lane = tid & 63;
    const int wm   = wave >> 1, wn = wave & 1;
    const int lrow = lane & 15, quad = lane >> 4;

    floatx4 acc[4][4];
    #pragma unroll
    for (int i = 0; i < 4; i++)
        #pragma unroll
        for (int j = 0; j < 4; j++)
            acc[i][j] = (floatx4){0.f, 0.f, 0.f, 0.f};

    const int srow = wave * 32 + (lane >> 2);
    const int scol = (lane & 3) * 8;
    const bf16* gA0 = A  + (size_t)(by * 128 + srow) * K + scol;
    const bf16* gA1 = gA0 + (size_t)16 * K;
    const bf16* gB0 = Bt + (size_t)(bx * 128 + srow) * K + scol;
    const bf16* gB1 = gB0 + (size_t)16 * K;
    char* lA0 = (char*)&sA[0][0] + wave * 2048 + lane * 16;
    char* lA1 = lA0 + 1024;
    char* lB0 = (char*)&sB[0][0] + wave * 2048 + lane * 16;
    char* lB1 = lB0 + 1024;

    for (int k0 = 0; k0 < K; k0 += 32) {
        __syncthreads();
        gl_lds16(gA0 + k0, lA0);
        gl_lds16(gA1 + k0, lA1);
        gl_lds16(gB0 + k0, lB0);
        gl_lds16(gB1 + k0, lB1);
        __syncthreads();
        bhalf8 af[4], bfr[4];
        #pragma unroll
        for (int t = 0; t < 4; t++) af[t]  = *(const bhalf8*)&sA[wm * 64 + t * 16 + lrow][quad * 8];
        #pragma unroll
        for (int t = 0; t < 4; t++) bfr[t] = *(const bhalf8*)&sB[wn * 64 + t * 16 + lrow][quad * 8];
        #pragma unroll
        for (int tm = 0; tm < 4; tm++)
            #pragma unroll
            for (int tn = 0; tn < 4; tn++)
                acc[tm][tn] = __builtin_amdgcn_mfma_f32_16x16x32_bf16(af[tm], bfr[tn], acc[tm][tn], 0, 0, 0);
    }

    #pragma unroll
    for (int tm = 0; tm < 4; tm++) {
        #pragma unroll
        for (int tn = 0; tn < 4; tn++) {
            const int col = bx * 128 + wn * 64 + tn * 16 + lrow;
            #pragma unroll
            for (int r = 0; r < 4; r++) {
                const int row = by * 128 + wm * 64 + tm * 16 + quad * 4 + r;
                C[(size_t)row * N + col] = f2b(acc[tm][tn][r]);
            }
        }
    }
}

// -------------------------------------------------------------------------
// s_src/s_tgt: wave-autonomous dot over f=256. p row-major (b,n,2048).
// grid (32 bh, 256); wave handles node n = by*4 + wave.
__global__ __launch_bounds__(256) void compute_sw(const bf16* __restrict__ p,
                                                  const void* __restrict__ a_src,
                                                  const void* __restrict__ a_tgt,
                                                  float* __restrict__ s_src_t,
                                                  float* __restrict__ s_tgt_t,
                                                  const int* __restrict__ flag)
{
    const int f32 = *flag;
    const int bh = blockIdx.x, b = bh >> 3, h = bh & 7;
    const int wave = threadIdx.x >> 6, lane = threadIdx.x & 63;
    const int n = blockIdx.y * 4 + wave;
    const bf16* pr = p + ((size_t)(b * 1024 + n)) * 2048 + h * 256;
    float ss = 0.f, st = 0.f;
    #pragma unroll
    for (int q = 0; q < 4; q++) {
        const int f = q * 64 + lane;
        float pv = b2f(pr[f]);
        ss = fmaf(pv, loadf(a_src, h * 256 + f, f32), ss);
        st = fmaf(pv, loadf(a_tgt, h * 256 + f, f32), st);
    }
    #pragma unroll
    for (int off = 32; off; off >>= 1) {
        ss += __shfl_down(ss, off, 64);
        st += __shfl_down(st, off, 64);
    }
    if (lane == 0) {
        s_src_t[bh * 1024 + n] = ss;
        s_tgt_t[bh * 1024 + n] = st;
    }
}

// -------------------------------------------------------------------------
// Barrier-free softmax: wave handles h = wave and wave+4; lane covers
// j = lane + 64q. No max-subtraction: scores are O(1) and mask <= 0, so
// exp cannot overflow; underflow to 0 is harmless.
// grid (4*128): b = bx>>7, itile = bx&127 (8 rows each).
__global__ __launch_bounds__(256) void softmax8_k(const float* __restrict__ s_src_t,
                                                  const float* __restrict__ s_tgt_t,
                                                  const void* __restrict__ mask,
                                                  bf16* __restrict__ wbuf,
                                                  float* __restrict__ invl,
                                                  const int* __restrict__ flag)
{
    const int f32 = *flag;
    const int b = blockIdx.x >> 7, itile = blockIdx.x & 127;
    const int wave = threadIdx.x >> 6, lane = threadIdx.x & 63;
    const int h0 = wave, h1 = wave + 4;
    float st0[16], st1[16];
    #pragma unroll
    for (int q = 0; q < 16; q++) {
        st0[q] = s_tgt_t[(b * 8 + h0) * 1024 + q * 64 + lane];
        st1[q] = s_tgt_t[(b * 8 + h1) * 1024 + q * 64 + lane];
    }
    for (int r = 0; r < 8; r++) {
        const int i = itile * 8 + r;
        const size_t moff = ((size_t)b * 1024 + i) * 1024;
        float mrow[16];
        #pragma unroll
        for (int q = 0; q < 16; q++) mrow[q] = loadf(mask, moff + q * 64 + lane, f32);
        #pragma unroll
        for (int hh = 0; hh < 2; hh++) {
            const int h = hh ? h1 : h0;
            const float ssr = s_src_t[(b * 8 + h) * 1024 + i];
            bf16* wb = wbuf + ((size_t)(b * 8 + h) << 20) + (size_t)i * 1024;
            float l = 0.f;
            #pragma unroll
            for (int q = 0; q < 16; q++) {
                float x = ssr + (hh ? st1[q] : st0[q]);
                x = (x > 0.f) ? x : 0.2f * x;          // leaky_relu(0.2)
                float e = __expf(x + mrow[q]);
                wb[q * 64 + lane] = f2b(e);
                l += e;
            }
            #pragma unroll
            for (int off = 32; off; off >>= 1) l += __shfl_down(l, off, 64);
            if (lane == 0) invl[(b * 8 + h) * 1024 + i] = 1.0f / l;
        }
    }
}

// -------------------------------------------------------------------------
// Layer-1 attention aggregation per (b,h): out = w(1024x1024) @ p_h(1024x256),
// epilogue: *invl[row] + skip + bias, ELU -> x2 (bf16).
__global__ __launch_bounds__(256) void attn_gemm(const bf16* __restrict__ wbuf,
                                                 const bf16* __restrict__ pT,
                                                 const float* __restrict__ invl,
                                                 const bf16* __restrict__ sk,
                                                 const void* __restrict__ bias,
                                                 bf16* __restrict__ x2,
                                                 const int* __restrict__ flag)
{
    __shared__ __align__(16) short sA[128][32];
    __shared__ __align__(16) short sB[128][32];
    const int tid  = threadIdx.x;
    const int bx   = blockIdx.x, by = blockIdx.y, bh = blockIdx.z;
    const int b = bh >> 3, h = bh & 7;
    const int wave = tid >> 6, lane = tid & 63;
    const int wm   = wave >> 1, wn = wave & 1;
    const int lrow = lane & 15, quad = lane >> 4;
    const int f32  = *flag;

    const bf16* A  = wbuf + ((size_t)bh << 20);
    const bf16* Bt = pT   + ((size_t)bh << 18);

    floatx4 acc[4][4];
    #pragma unroll
    for (int i = 0; i < 4; i++)
        #pragma unroll
        for (int j = 0; j < 4; j++)
            acc[i][j] = (floatx4){0.f, 0.f, 0.f, 0.f};

    const int srow = wave * 32 + (lane >> 2);
    const int scol = (lane & 3) * 8;
    const bf16* gA0 = A  + (size_t)(by * 128 + srow) * 1024 + scol;
    const bf16* gA1 = gA0 + (size_t)16 * 1024;
    const bf16* gB0 = Bt + (size_t)(bx * 128 + srow) * 1024 + scol;
    const bf16* gB1 = gB0 + (size_t)16 * 1024;
    char* lA0 = (char*)&sA[0][0] + wave * 2048 + lane * 16;
    char* lA1 = lA0 + 1024;
    char* lB0 = (char*)&sB[0][0] + wave * 2048 + lane * 16;
    char* lB1 = lB0 + 1024;

    for (int k0 = 0; k0 < 1024; k0 += 32) {
        __syncthreads();
        gl_lds16(gA0 + k0, lA0);
        gl_lds16(gA1 + k0, lA1);
        gl_lds16(gB0 + k0, lB0);
        gl_lds16(gB1 + k0, lB1);
        __syncthreads();
        bhalf8 af[4], bfr[4];
        #pragma unroll
        for (int t = 0; t < 4; t++) af[t]  = *(const bhalf8*)&sA[wm * 64 + t * 16 + lrow][quad * 8];
        #pragma unroll
        for (int t = 0; t < 4; t++) bfr[t] = *(const bhalf8*)&sB[wn * 64 + t * 16 + lrow][quad * 8];
        #pragma unroll
        for (int tm = 0; tm < 4; tm++)
            #pragma unroll
            for (int tn = 0; tn < 4; tn++)
                acc[tm][tn] = __builtin_amdgcn_mfma_f32_16x16x32_bf16(af[tm], bfr[tn], acc[tm][tn], 0, 0, 0);
    }

    #pragma unroll
    for (int tm = 0; tm < 4; tm++) {
        #pragma unroll
        for (int r = 0; r < 4; r++) {
            const int row = by * 128 + wm * 64 + tm * 16 + quad * 4 + r;
            const float il = invl[bh * 1024 + row];
            #pragma unroll
            for (int tn = 0; tn < 4; tn++) {
                const int col = bx * 128 + wn * 64 + tn * 16 + lrow;
                const int hf = h * 256 + col;
                const size_t idx = ((size_t)(b * 1024 + row)) * 2048 + hf;
                float v = acc[tm][tn][r] * il + b2f(sk[idx]) + loadf(bias, hf, f32);
                v = (v > 0.f) ? v : expm1f(v);     // ELU
                x2[idx] = f2b(v);
            }
        }
    }
}

// -------------------------------------------------------------------------
__global__ void zero_f(float* __restrict__ p, int n)
{
    int idx = blockIdx.x * blockDim.x + threadIdx.x;
    if (idx < n) p[idx] = 0.f;
}

// c[bh][j] = sum_i invl[bh,i] * w[bh,i,j]   (column sums of softmax matrix)
__global__ __launch_bounds__(256) void colsum_k(const bf16* __restrict__ wbuf,
                                                const float* __restrict__ invl,
                                                float* __restrict__ c)
{
    const int bh = blockIdx.x;
    const int j = blockIdx.y * 256 + threadIdx.x;
    const bf16* wb = wbuf + ((size_t)bh << 20) + j;
    const float* il = invl + bh * 1024;
    float acc = 0.f;
    #pragma unroll 8
    for (int i = 0; i < 1024; i++)
        acc = fmaf(b2f(wb[(size_t)i << 10]), il[i], acc);
    c[bh * 1024 + j] = acc;
}

// xbar[b][k] += sum_{i in chunk} x2[b,i,k]
__global__ __launch_bounds__(256) void rowsum_k(const bf16* __restrict__ x2,
                                                float* __restrict__ xbar)
{
    const int b = blockIdx.x, k = blockIdx.y * 256 + threadIdx.x;
    const int i0 = blockIdx.z * 256;
    const bf16* xp = x2 + ((size_t)(b * 1024 + i0)) * 2048 + k;
    float acc = 0.f;
    #pragma unroll 8
    for (int i = 0; i < 256; i++) acc += b2f(xp[(size_t)i * 2048]);
    atomicAdd(&xbar[b * 2048 + k], acc);
}

// gA[bh][f] += sum_{j in chunk} c[bh,j] * p2[b,j,h*256+f]
__global__ __launch_bounds__(256) void attn2_vec(const bf16* __restrict__ p2,
                                                 const float* __restrict__ c,
                                                 float* __restrict__ gA)
{
    const int bh = blockIdx.x, b = bh >> 3, h = bh & 7;
    const int j0 = blockIdx.y * 128;
    const int f = threadIdx.x;
    const bf16* pp = p2 + ((size_t)(b * 1024 + j0)) * 2048 + h * 256 + f;
    const float* cc = c + bh * 1024 + j0;
    float acc = 0.f;
    #pragma unroll 4
    for (int j = 0; j < 128; j++)
        acc = fmaf(cc[j], b2f(pp[(size_t)j * 2048]), acc);
    atomicAdd(&gA[bh * 256 + f], acc);
}

// gS[b][hf] += sum_{k in chunk} xbar[b,k] * skip2[k,hf]
__global__ __launch_bounds__(256) void skipvec_k(const void* __restrict__ skip2,
                                                 const float* __restrict__ xbar,
                                                 float* __restrict__ gS,
                                                 const int* __restrict__ flag)
{
    const int f32 = *flag;
    const int b = blockIdx.x, hft = blockIdx.y, kc = blockIdx.z;
    const int hf = hft * 256 + threadIdx.x;
    float acc = 0.f;
    #pragma unroll 4
    for (int kk = 0; kk < 256; kk++) {
        const int k = kc * 256 + kk;
        acc = fmaf(xbar[b * 2048 + k], loadf(skip2, (size_t)k * 2048 + hf, f32), acc);
    }
    atomicAdd(&gS[b * 2048 + hf], acc);
}

// g[b,f] = (sum_h gA + sum_h gS)/(8*1024) + b2[f]; out = g@Wc + bc
__global__ __launch_bounds__(256) void classify2_k(const float* __restrict__ gA,
                                                   const float* __restrict__ gS,
                                                   const void* __restrict__ b2,
                                                   const void* __restrict__ Wc,
                                                   const void* __restrict__ bc,
                                                   void* __restrict__ out,
                                                   const int* __restrict__ flag)
{
    __shared__ float gv[256];
    const int f32 = *flag;
    const int b = blockIdx.x, f = threadIdx.x;
    float s = 0.f;
    #pragma unroll
    for (int h = 0; h < 8; h++)
        s += gA[(b * 8 + h) * 256 + f] + gS[b * 2048 + h * 256 + f];
    gv[f] = s * (1.0f / 8192.0f) + loadf(b2, f, f32);
    __syncthreads();
    if (f < 10) {
        float acc = loadf(bc, f, f32);
        for (int k = 0; k < 256; k++)
            acc = fmaf(gv[k], loadf(Wc, k * 10 + f, f32), acc);
        if (f32) ((float*)out)[b * 10 + f] = acc;
        else     ((bf16*)out)[b * 10 + f] = f2b(acc);
    }
}

// -------------------------------------------------------------------------
extern "C" void kernel_launch(void* const* d_in, const int* in_sizes, int n_in,
                              void* d_out, int out_size, void* d_ws, size_t ws_size,
                              hipStream_t stream)
{
    (void)in_sizes; (void)n_in; (void)out_size; (void)ws_size;
    const void* feat   = d_in[0];
    const void* mask   = d_in[2];
    const void* W1     = d_in[3];
    const void* a_src1 = d_in[4];
    const void* a_tgt1 = d_in[5];
    const void* skip1  = d_in[6];
    const void* b1     = d_in[7];
    const void* W2     = d_in[8];
    const void* a_src2 = d_in[9];
    const void* a_tgt2 = d_in[10];
    const void* skip2  = d_in[11];
    const void* b2v    = d_in[12];
    const void* Wc     = d_in[13];
    const void* bc     = d_in[14];

    char* ws = (char*)d_ws;
    size_t off = 0;
    auto alloc = [&](size_t bytes) -> void* {
        void* p = ws + off;
        off += (bytes + 255) & ~(size_t)255;
        return p;
    };
    int*   flag = (int*)alloc(256);
    bf16*  featc= (bf16*)alloc(4096ull * 256 * 2);
    bf16*  W1t  = (bf16*)alloc(2048ull * 256 * 2);
    bf16*  S1t  = (bf16*)alloc(2048ull * 256 * 2);
    bf16*  W2t  = (bf16*)alloc(2048ull * 2048 * 2);
    bf16*  p1   = (bf16*)alloc(4096ull * 2048 * 2);
    bf16*  sk1  = (bf16*)alloc(4096ull * 2048 * 2);
    bf16*  x2   = (bf16*)alloc(4096ull * 2048 * 2);
    bf16*  pT   = (bf16*)alloc(4096ull * 2048 * 2);
    bf16*  wbuf = (bf16*)alloc(32ull * 1024 * 1024 * 2);
    float* invl = (float*)alloc(32ull * 1024 * 4);
    float* ss   = (float*)alloc(32ull * 1024 * 4);
    float* st   = (float*)alloc(32ull * 1024 * 4);
    float* cbuf = (float*)alloc(32ull * 1024 * 4);
    // gA, gS, xbar contiguous so one zero_f covers all three
    float* gA   = (float*)alloc(32ull * 256 * 4);      // 8192 floats
    float* gS   = (float*)alloc(4ull * 2048 * 4);      // 8192 floats
    float* xbar = (float*)alloc(4ull * 2048 * 4);      // 8192 floats
    bf16* p2 = p1;    // reuse: p1 dead after transpose_p + compute_sw (L1)

    detect_k<<<1, 64, 0, stream>>>(W1, flag);
    cvt_k<<<4096, 256, 0, stream>>>(feat, featc, 4096 * 256, flag);
    zero_f<<<96, 256, 0, stream>>>(gA, 3 * 8192);

    transpose_k<<<dim3(64, 8),  256, 0, stream>>>(W1,    W1t, 256, 2048, flag);
    transpose_k<<<dim3(64, 8),  256, 0, stream>>>(skip1, S1t, 256, 2048, flag);
    transpose_k<<<dim3(64, 64), 256, 0, stream>>>(W2,    W2t, 2048, 2048, flag);

    // ---- layer 1 ----
    gemm_bt2<<<dim3(16, 32, 2), 256, 0, stream>>>(featc, W1t, S1t, p1, sk1, 4096, 2048, 256);
    transpose_p<<<dim3(64, 32, 4), 256, 0, stream>>>(p1, pT);
    compute_sw<<<dim3(32, 256), 256, 0, stream>>>(p1, a_src1, a_tgt1, ss, st, flag);
    softmax8_k<<<512, 256, 0, stream>>>(ss, st, mask, wbuf, invl, flag);
    attn_gemm<<<dim3(2, 8, 32), 256, 0, stream>>>(wbuf, pT, invl, sk1, b1, x2, flag);

    // ---- layer 2 (pool-collapsed) ----
    gemm_bt2<<<dim3(16, 32, 1), 256, 0, stream>>>(x2, W2t, W2t, p2, p2, 4096, 2048, 2048);
    compute_sw<<<dim3(32, 256), 256, 0, stream>>>(p2, a_src2, a_tgt2, ss, st, flag);
    softmax8_k<<<512, 256, 0, stream>>>(ss, st, mask, wbuf, invl, flag);
    colsum_k<<<dim3(32, 4), 256, 0, stream>>>(wbuf, invl, cbuf);
    rowsum_k<<<dim3(4, 8, 4), 256, 0, stream>>>(x2, xbar);
    attn2_vec<<<dim3(32, 8), 256, 0, stream>>>(p2, cbuf, gA);
    skipvec_k<<<dim3(4, 8, 8), 256, 0, stream>>>(skip2, xbar, gS, flag);

    // ---- classify ----
    classify2_k<<<4, 256, 0, stream>>>(gA, gS, b2v, Wc, bc, d_out, flag);
}

// Round 6
// 453.497 us; speedup vs baseline: 2.5124x; 1.0662x over previous
//
#include <hip/hip_runtime.h>
#include <hip/hip_bf16.h>
#include <stdint.h>
#include <stddef.h>

typedef __hip_bfloat16 bf16;
typedef __attribute__((ext_vector_type(8))) short bhalf8;
typedef __attribute__((ext_vector_type(4))) float floatx4;

static __device__ __forceinline__ float b2f(bf16 v) { return __bfloat162float(v); }
static __device__ __forceinline__ bf16  f2b(float v) { return __float2bfloat16(v); }
static __device__ __forceinline__ short f2s(float v) {
    union { bf16 b; short s; } u; u.b = __float2bfloat16(v); return u.s;
}

// dtype-agnostic scalar load: flag==1 -> fp32 data, flag==0 -> bf16 data
static __device__ __forceinline__ float loadf(const void* p, size_t i, int f32) {
    return f32 ? ((const float*)p)[i] : b2f(((const bf16*)p)[i]);
}

// async global->LDS, 16B per lane. LDS dest must be wave-uniform base + lane*16.
static __device__ __forceinline__ void gl_lds16(const void* g, void* l) {
    __builtin_amdgcn_global_load_lds(
        (const __attribute__((address_space(1))) void*)g,
        (__attribute__((address_space(3))) void*)l, 16, 0, 0);
}

// load 16 consecutive mask values starting at 16-aligned index
static __device__ __forceinline__ void load_mask16(const void* mask, size_t idx,
                                                   int f32, float* mv) {
    if (f32) {
        const float4* p = (const float4*)((const float*)mask + idx);
        #pragma unroll
        for (int q = 0; q < 4; q++) {
            float4 v = p[q];
            mv[q * 4 + 0] = v.x; mv[q * 4 + 1] = v.y;
            mv[q * 4 + 2] = v.z; mv[q * 4 + 3] = v.w;
        }
    } else {
        const bf16* p = (const bf16*)mask + idx;
        #pragma unroll
        for (int t = 0; t < 16; t++) mv[t] = b2f(p[t]);
    }
}

// -------------------------------------------------------------------------
__global__ void detect_k(const void* w1raw, int* flag)
{
    if (threadIdx.x == 0 && blockIdx.x == 0) {
        const unsigned short* s = (const unsigned short*)w1raw;
        int bad = 0;
        for (int i = 0; i < 256; i++) {
            int e = (s[i] >> 7) & 0xFF;
            if (e > 0x85 || (e != 0 && e < 0x60)) bad++;
        }
        *flag = (bad > 16) ? 1 : 0;
    }
}

__global__ __launch_bounds__(256) void cvt_k(const void* __restrict__ src,
                                             bf16* __restrict__ dst, int n,
                                             const int* __restrict__ flag)
{
    const int f = *flag;
    int i = blockIdx.x * 256 + threadIdx.x;
    if (i < n) dst[i] = f ? f2b(((const float*)src)[i]) : ((const bf16*)src)[i];
}

// -------------------------------------------------------------------------
__global__ __launch_bounds__(256) void transpose_k(const void* __restrict__ in,
                                                   bf16* __restrict__ out,
                                                   int R, int C,
                                                   const int* __restrict__ flag)
{
    __shared__ bf16 tile[32][33];
    const int f = *flag;
    const int tx = threadIdx.x & 31;
    const int ty = threadIdx.x >> 5;
    const int c0 = blockIdx.x * 32;
    const int r0 = blockIdx.y * 32;
    #pragma unroll
    for (int yy = ty; yy < 32; yy += 8)
        tile[yy][tx] = f2b(loadf(in, (size_t)(r0 + yy) * C + c0 + tx, f));
    __syncthreads();
    #pragma unroll
    for (int yy = ty; yy < 32; yy += 8)
        out[(size_t)(c0 + yy) * R + r0 + tx] = tile[tx][yy];
}

// batched bf16 transpose: per b, in (1024 x 2048) -> out (2048 x 1024)
__global__ __launch_bounds__(256) void transpose_p(const bf16* __restrict__ in,
                                                   bf16* __restrict__ out)
{
    __shared__ bf16 tile[32][33];
    const int bz = blockIdx.z;
    const int tx = threadIdx.x & 31;
    const int ty = threadIdx.x >> 5;
    const int c0 = blockIdx.x * 32;
    const int r0 = blockIdx.y * 32;
    const bf16* ib = in + (size_t)bz * 1024 * 2048;
    bf16* ob = out + (size_t)bz * 1024 * 2048;
    #pragma unroll
    for (int yy = ty; yy < 32; yy += 8)
        tile[yy][tx] = ib[(size_t)(r0 + yy) * 2048 + c0 + tx];
    __syncthreads();
    #pragma unroll
    for (int yy = ty; yy < 32; yy += 8)
        ob[(size_t)(c0 + yy) * 1024 + r0 + tx] = tile[tx][yy];
}

// -------------------------------------------------------------------------
// Paired GEMM: C = A@B[z], Bt row-major (N x K). 128x128x32 tile, 4 waves,
// mfma 16x16x32 bf16, global_load_lds width-16 staging (m97 structure).
__global__ __launch_bounds__(256) void gemm_bt2(const bf16* __restrict__ A,
                                                const bf16* __restrict__ Bt0,
                                                const bf16* __restrict__ Bt1,
                                                bf16* __restrict__ C0,
                                                bf16* __restrict__ C1,
                                                int M, int N, int K)
{
    __shared__ __align__(16) short sA[128][32];
    __shared__ __align__(16) short sB[128][32];
    const int tid  = threadIdx.x;
    const int bx   = blockIdx.x, by = blockIdx.y;
    const bf16* Bt = blockIdx.z ? Bt1 : Bt0;
    bf16* C        = blockIdx.z ? C1  : C0;
    const int wave = tid >> 6, lane = tid & 63;
    const int wm   = wave >> 1, wn = wave & 1;
    const int lrow = lane & 15, quad = lane >> 4;

    floatx4 acc[4][4];
    #pragma unroll
    for (int i = 0; i < 4; i++)
        #pragma unroll
        for (int j = 0; j < 4; j++)
            acc[i][j] = (floatx4){0.f, 0.f, 0.f, 0.f};

    const int srow = wave * 32 + (lane >> 2);
    const int scol = (lane & 3) * 8;
    const bf16* gA0 = A  + (size_t)(by * 128 + srow) * K + scol;
    const bf16* gA1 = gA0 + (size_t)16 * K;
    const bf16* gB0 = Bt + (size_t)(bx * 128 + srow) * K + scol;
    const bf16* gB1 = gB0 + (size_t)16 * K;
    char* lA0 = (char*)&sA[0][0] + wave * 2048 + lane * 16;
    char* lA1 = lA0 + 1024;
    char* lB0 = (char*)&sB[0][0] + wave * 2048 + lane * 16;
    char* lB1 = lB0 + 1024;

    for (int k0 = 0; k0 < K; k0 += 32) {
        __syncthreads();
        gl_lds16(gA0 + k0, lA0);
        gl_lds16(gA1 + k0, lA1);
        gl_lds16(gB0 + k0, lB0);
        gl_lds16(gB1 + k0, lB1);
        __syncthreads();
        bhalf8 af[4], bfr[4];
        #pragma unroll
        for (int t = 0; t < 4; t++) af[t]  = *(const bhalf8*)&sA[wm * 64 + t * 16 + lrow][quad * 8];
        #pragma unroll
        for (int t = 0; t < 4; t++) bfr[t] = *(const bhalf8*)&sB[wn * 64 + t * 16 + lrow][quad * 8];
        #pragma unroll
        for (int tm = 0; tm < 4; tm++)
            #pragma unroll
            for (int tn = 0; tn < 4; tn++)
                acc[tm][tn] = __builtin_amdgcn_mfma_f32_16x16x32_bf16(af[tm], bfr[tn], acc[tm][tn], 0, 0, 0);
    }

    #pragma unroll
    for (int tm = 0; tm < 4; tm++) {
        #pragma unroll
        for (int tn = 0; tn < 4; tn++) {
            const int col = bx * 128 + wn * 64 + tn * 16 + lrow;
            #pragma unroll
            for (int r = 0; r < 4; r++) {
                const int row = by * 128 + wm * 64 + tm * 16 + quad * 4 + r;
                C[(size_t)row * N + col] = f2b(acc[tm][tn][r]);
            }
        }
    }
}

// -------------------------------------------------------------------------
// s_src/s_tgt: wave-autonomous dot over f=256. p row-major (b,n,2048).
__global__ __launch_bounds__(256) void compute_sw(const bf16* __restrict__ p,
                                                  const void* __restrict__ a_src,
                                                  const void* __restrict__ a_tgt,
                                                  float* __restrict__ s_src_t,
                                                  float* __restrict__ s_tgt_t,
                                                  const int* __restrict__ flag)
{
    const int f32 = *flag;
    const int bh = blockIdx.x, b = bh >> 3, h = bh & 7;
    const int wave = threadIdx.x >> 6, lane = threadIdx.x & 63;
    const int n = blockIdx.y * 4 + wave;
    const bf16* pr = p + ((size_t)(b * 1024 + n)) * 2048 + h * 256;
    float ss = 0.f, st = 0.f;
    #pragma unroll
    for (int q = 0; q < 4; q++) {
        const int f = q * 64 + lane;
        float pv = b2f(pr[f]);
        ss = fmaf(pv, loadf(a_src, h * 256 + f, f32), ss);
        st = fmaf(pv, loadf(a_tgt, h * 256 + f, f32), st);
    }
    #pragma unroll
    for (int off = 32; off; off >>= 1) {
        ss += __shfl_down(ss, off, 64);
        st += __shfl_down(st, off, 64);
    }
    if (lane == 0) {
        s_src_t[bh * 1024 + n] = ss;
        s_tgt_t[bh * 1024 + n] = st;
    }
}

// -------------------------------------------------------------------------
// Fused layer-1 attention: per block (bx,by,bh), out rows by*128..+127,
// cols f = bx*128..+127. Softmax numerators generated inline in LDS each
// K-step (no wbuf); row denominator accumulated inline; epilogue
// *invl + skip + bias + ELU -> x2.
__global__ __launch_bounds__(256) void attn_fused(const float* __restrict__ s_src_t,
                                                  const float* __restrict__ s_tgt_t,
                                                  const void* __restrict__ mask,
                                                  const bf16* __restrict__ pT,
                                                  const bf16* __restrict__ sk,
                                                  const void* __restrict__ bias,
                                                  bf16* __restrict__ x2,
                                                  const int* __restrict__ flag)
{
    __shared__ __align__(16) short sA[128][32];   // e-tile (bf16 numerators)
    __shared__ __align__(16) short sB[128][32];   // pT tile
    __shared__ float sStgt[1024];
    __shared__ float sInvl[128];

    const int tid = threadIdx.x;
    const int bx = blockIdx.x, by = blockIdx.y, bh = blockIdx.z;
    const int b = bh >> 3, h = bh & 7;
    const int f32 = *flag;
    const int wave = tid >> 6, lane = tid & 63;
    const int wm = wave >> 1, wn = wave & 1;
    const int lrow = lane & 15, quad = lane >> 4;

    #pragma unroll
    for (int q = 0; q < 4; q++)
        sStgt[q * 256 + tid] = s_tgt_t[bh * 1024 + q * 256 + tid];

    // score-gen assignment: 2 threads per row
    const int irow = tid >> 1;                 // 0..127
    const int jh16 = (tid & 1) * 16;           // 0 or 16
    const float ssr = s_src_t[bh * 1024 + by * 128 + irow];
    const size_t mrow0 = ((size_t)(b * 1024 + by * 128 + irow)) << 10;

    // B staging (global_load_lds)
    const int srow = wave * 32 + (lane >> 2);
    const int scol = (lane & 3) * 8;
    const bf16* gB0 = pT + ((size_t)bh << 18) + (size_t)(bx * 128 + srow) * 1024 + scol;
    const bf16* gB1 = gB0 + (size_t)16 * 1024;
    char* lB0 = (char*)&sB[0][0] + wave * 2048 + lane * 16;
    char* lB1 = lB0 + 1024;

    floatx4 acc[4][4];
    #pragma unroll
    for (int i = 0; i < 4; i++)
        #pragma unroll
        for (int j = 0; j < 4; j++)
            acc[i][j] = (floatx4){0.f, 0.f, 0.f, 0.f};

    float lacc = 0.f;
    for (int k0 = 0; k0 < 1024; k0 += 32) {
        float mv[16];
        load_mask16(mask, mrow0 + k0 + jh16, f32, mv);   // before barrier: overlap
        __syncthreads();                                 // prev LDS consumers done
        gl_lds16(gB0 + k0, lB0);
        gl_lds16(gB1 + k0, lB1);
        short ev[16];
        #pragma unroll
        for (int t = 0; t < 16; t++) {
            float x = ssr + sStgt[k0 + jh16 + t];
            x = (x > 0.f) ? x : 0.2f * x;                // leaky_relu(0.2)
            float e = __expf(x + mv[t]);
            lacc += e;
            ev[t] = f2s(e);
        }
        *(int4*)&sA[irow][jh16]     = *(int4*)&ev[0];
        *(int4*)&sA[irow][jh16 + 8] = *(int4*)&ev[8];
        __syncthreads();                                 // A writes + B arrival
        bhalf8 af[4], bfr[4];
        #pragma unroll
        for (int t = 0; t < 4; t++) af[t]  = *(const bhalf8*)&sA[wm * 64 + t * 16 + lrow][quad * 8];
        #pragma unroll
        for (int t = 0; t < 4; t++) bfr[t] = *(const bhalf8*)&sB[wn * 64 + t * 16 + lrow][quad * 8];
        #pragma unroll
        for (int tm = 0; tm < 4; tm++)
            #pragma unroll
            for (int tn = 0; tn < 4; tn++)
                acc[tm][tn] = __builtin_amdgcn_mfma_f32_16x16x32_bf16(af[tm], bfr[tn], acc[tm][tn], 0, 0, 0);
    }

    // finalize row denominators: pair threads share a row (lane^1)
    lacc += __shfl_xor(lacc, 1, 64);
    if ((tid & 1) == 0) sInvl[irow] = 1.0f / lacc;
    __syncthreads();

    #pragma unroll
    for (int tm = 0; tm < 4; tm++) {
        #pragma unroll
        for (int r = 0; r < 4; r++) {
            const int rl = wm * 64 + tm * 16 + quad * 4 + r;   // 0..127
            const int row = by * 128 + rl;
            const float il = sInvl[rl];
            #pragma unroll
            for (int tn = 0; tn < 4; tn++) {
                const int col = bx * 128 + wn * 64 + tn * 16 + lrow;   // 0..255
                const int hf = h * 256 + col;
                const size_t idx = ((size_t)(b * 1024 + row)) * 2048 + hf;
                float v = acc[tm][tn][r] * il + b2f(sk[idx]) + loadf(bias, hf, f32);
                v = (v > 0.f) ? v : expm1f(v);     // ELU
                x2[idx] = f2b(v);
            }
        }
    }
}

// -------------------------------------------------------------------------
// Layer-2 denominators only (no numerator store). Wave handles h=wave, wave+4.
__global__ __launch_bounds__(256) void lpass_k(const float* __restrict__ s_src_t,
                                               const float* __restrict__ s_tgt_t,
                                               const void* __restrict__ mask,
                                               float* __restrict__ invl,
                                               const int* __restrict__ flag)
{
    const int f32 = *flag;
    const int b = blockIdx.x >> 7, itile = blockIdx.x & 127;
    const int wave = threadIdx.x >> 6, lane = threadIdx.x & 63;
    const int h0 = wave, h1 = wave + 4;
    float st0[16], st1[16];
    #pragma unroll
    for (int q = 0; q < 16; q++) {
        st0[q] = s_tgt_t[(b * 8 + h0) * 1024 + q * 64 + lane];
        st1[q] = s_tgt_t[(b * 8 + h1) * 1024 + q * 64 + lane];
    }
    for (int r = 0; r < 8; r++) {
        const int i = itile * 8 + r;
        const size_t moff = ((size_t)b * 1024 + i) * 1024;
        float mrow[16];
        #pragma unroll
        for (int q = 0; q < 16; q++) mrow[q] = loadf(mask, moff + q * 64 + lane, f32);
        #pragma unroll
        for (int hh = 0; hh < 2; hh++) {
            const int h = hh ? h1 : h0;
            const float ssr = s_src_t[(b * 8 + h) * 1024 + i];
            float l = 0.f;
            #pragma unroll
            for (int q = 0; q < 16; q++) {
                float x = ssr + (hh ? st1[q] : st0[q]);
                x = (x > 0.f) ? x : 0.2f * x;
                l += __expf(x + mrow[q]);
            }
            #pragma unroll
            for (int off = 32; off; off >>= 1) l += __shfl_down(l, off, 64);
            if (lane == 0) invl[(b * 8 + h) * 1024 + i] = 1.0f / l;
        }
    }
}

// -------------------------------------------------------------------------
// c[bh][j] += sum_{i in chunk} invl[i]*e[i,j], e regenerated inline.
// grid (32, 4 jt, 4 it); thread = j.
__global__ __launch_bounds__(256) void colsum2_k(const float* __restrict__ s_src_t,
                                                 const float* __restrict__ s_tgt_t,
                                                 const void* __restrict__ mask,
                                                 const float* __restrict__ invl,
                                                 float* __restrict__ c,
                                                 const int* __restrict__ flag)
{
    __shared__ float sS[256], sIl[256];
    const int f32 = *flag;
    const int bh = blockIdx.x, b = bh >> 3;
    const int j = blockIdx.y * 256 + threadIdx.x;
    const int i0 = blockIdx.z * 256;
    sS[threadIdx.x]  = s_src_t[bh * 1024 + i0 + threadIdx.x];
    sIl[threadIdx.x] = invl[bh * 1024 + i0 + threadIdx.x];
    __syncthreads();
    const float stj = s_tgt_t[bh * 1024 + j];
    float acc = 0.f;
    #pragma unroll 4
    for (int ii = 0; ii < 256; ii++) {
        float x = sS[ii] + stj;
        x = (x > 0.f) ? x : 0.2f * x;
        float e = __expf(x + loadf(mask, (((size_t)(b * 1024 + i0 + ii)) << 10) + j, f32));
        acc = fmaf(sIl[ii], e, acc);
    }
    atomicAdd(&c[bh * 1024 + j], acc);
}

// -------------------------------------------------------------------------
__global__ void zero_f(float* __restrict__ p, int n)
{
    int idx = blockIdx.x * blockDim.x + threadIdx.x;
    if (idx < n) p[idx] = 0.f;
}

// xbar[b][k] += sum_{i in chunk} x2[b,i,k]
__global__ __launch_bounds__(256) void rowsum_k(const bf16* __restrict__ x2,
                                                float* __restrict__ xbar)
{
    const int b = blockIdx.x, k = blockIdx.y * 256 + threadIdx.x;
    const int i0 = blockIdx.z * 256;
    const bf16* xp = x2 + ((size_t)(b * 1024 + i0)) * 2048 + k;
    float acc = 0.f;
    #pragma unroll 8
    for (int i = 0; i < 256; i++) acc += b2f(xp[(size_t)i * 2048]);
    atomicAdd(&xbar[b * 2048 + k], acc);
}

// gA[bh][f] += sum_{j in chunk} c[bh,j] * p2[b,j,h*256+f]
__global__ __launch_bounds__(256) void attn2_vec(const bf16* __restrict__ p2,
                                                 const float* __restrict__ c,
                                                 float* __restrict__ gA)
{
    const int bh = blockIdx.x, b = bh >> 3, h = bh & 7;
    const int j0 = blockIdx.y * 128;
    const int f = threadIdx.x;
    const bf16* pp = p2 + ((size_t)(b * 1024 + j0)) * 2048 + h * 256 + f;
    const float* cc = c + bh * 1024 + j0;
    float acc = 0.f;
    #pragma unroll 4
    for (int j = 0; j < 128; j++)
        acc = fmaf(cc[j], b2f(pp[(size_t)j * 2048]), acc);
    atomicAdd(&gA[bh * 256 + f], acc);
}

// gS[b][hf] += sum_{k in chunk} xbar[b,k] * skip2[k,hf]
__global__ __launch_bounds__(256) void skipvec_k(const void* __restrict__ skip2,
                                                 const float* __restrict__ xbar,
                                                 float* __restrict__ gS,
                                                 const int* __restrict__ flag)
{
    const int f32 = *flag;
    const int b = blockIdx.x, hft = blockIdx.y, kc = blockIdx.z;
    const int hf = hft * 256 + threadIdx.x;
    float acc = 0.f;
    #pragma unroll 4
    for (int kk = 0; kk < 256; kk++) {
        const int k = kc * 256 + kk;
        acc = fmaf(xbar[b * 2048 + k], loadf(skip2, (size_t)k * 2048 + hf, f32), acc);
    }
    atomicAdd(&gS[b * 2048 + hf], acc);
}

// g[b,f] = (sum_h gA + sum_h gS)/(8*1024) + b2[f]; out = g@Wc + bc
__global__ __launch_bounds__(256) void classify2_k(const float* __restrict__ gA,
                                                   const float* __restrict__ gS,
                                                   const void* __restrict__ b2,
                                                   const void* __restrict__ Wc,
                                                   const void* __restrict__ bc,
                                                   void* __restrict__ out,
                                                   const int* __restrict__ flag)
{
    __shared__ float gv[256];
    const int f32 = *flag;
    const int b = blockIdx.x, f = threadIdx.x;
    float s = 0.f;
    #pragma unroll
    for (int h = 0; h < 8; h++)
        s += gA[(b * 8 + h) * 256 + f] + gS[b * 2048 + h * 256 + f];
    gv[f] = s * (1.0f / 8192.0f) + loadf(b2, f, f32);
    __syncthreads();
    if (f < 10) {
        float acc = loadf(bc, f, f32);
        for (int k = 0; k < 256; k++)
            acc = fmaf(gv[k], loadf(Wc, k * 10 + f, f32), acc);
        if (f32) ((float*)out)[b * 10 + f] = acc;
        else     ((bf16*)out)[b * 10 + f] = f2b(acc);
    }
}

// -------------------------------------------------------------------------
extern "C" void kernel_launch(void* const* d_in, const int* in_sizes, int n_in,
                              void* d_out, int out_size, void* d_ws, size_t ws_size,
                              hipStream_t stream)
{
    (void)in_sizes; (void)n_in; (void)out_size; (void)ws_size;
    const void* feat   = d_in[0];
    const void* mask   = d_in[2];
    const void* W1     = d_in[3];
    const void* a_src1 = d_in[4];
    const void* a_tgt1 = d_in[5];
    const void* skip1  = d_in[6];
    const void* b1     = d_in[7];
    const void* W2     = d_in[8];
    const void* a_src2 = d_in[9];
    const void* a_tgt2 = d_in[10];
    const void* skip2  = d_in[11];
    const void* b2v    = d_in[12];
    const void* Wc     = d_in[13];
    const void* bc     = d_in[14];

    char* ws = (char*)d_ws;
    size_t off = 0;
    auto alloc = [&](size_t bytes) -> void* {
        void* p = ws + off;
        off += (bytes + 255) & ~(size_t)255;
        return p;
    };
    int*   flag = (int*)alloc(256);
    bf16*  featc= (bf16*)alloc(4096ull * 256 * 2);
    bf16*  W1t  = (bf16*)alloc(2048ull * 256 * 2);
    bf16*  S1t  = (bf16*)alloc(2048ull * 256 * 2);
    bf16*  W2t  = (bf16*)alloc(2048ull * 2048 * 2);
    bf16*  p1   = (bf16*)alloc(4096ull * 2048 * 2);
    bf16*  sk1  = (bf16*)alloc(4096ull * 2048 * 2);
    bf16*  x2   = (bf16*)alloc(4096ull * 2048 * 2);
    bf16*  pT   = (bf16*)alloc(4096ull * 2048 * 2);
    float* invl = (float*)alloc(32ull * 1024 * 4);
    float* ss   = (float*)alloc(32ull * 1024 * 4);
    float* st   = (float*)alloc(32ull * 1024 * 4);
    // cbuf, gA, gS, xbar contiguous: one zero_f covers all
    float* cbuf = (float*)alloc(32ull * 1024 * 4);     // 32768 floats
    float* gA   = (float*)alloc(32ull * 256 * 4);      // 8192
    float* gS   = (float*)alloc(4ull * 2048 * 4);      // 8192
    float* xbar = (float*)alloc(4ull * 2048 * 4);      // 8192
    bf16* p2 = p1;    // reuse: p1 dead after transpose_p + compute_sw (L1)

    detect_k<<<1, 64, 0, stream>>>(W1, flag);
    cvt_k<<<4096, 256, 0, stream>>>(feat, featc, 4096 * 256, flag);
    zero_f<<<224, 256, 0, stream>>>(cbuf, 32768 + 3 * 8192);

    transpose_k<<<dim3(64, 8),  256, 0, stream>>>(W1,    W1t, 256, 2048, flag);
    transpose_k<<<dim3(64, 8),  256, 0, stream>>>(skip1, S1t, 256, 2048, flag);
    transpose_k<<<dim3(64, 64), 256, 0, stream>>>(W2,    W2t, 2048, 2048, flag);

    // ---- layer 1 ----
    gemm_bt2<<<dim3(16, 32, 2), 256, 0, stream>>>(featc, W1t, S1t, p1, sk1, 4096, 2048, 256);
    transpose_p<<<dim3(64, 32, 4), 256, 0, stream>>>(p1, pT);
    compute_sw<<<dim3(32, 256), 256, 0, stream>>>(p1, a_src1, a_tgt1, ss, st, flag);
    attn_fused<<<dim3(2, 8, 32), 256, 0, stream>>>(ss, st, mask, pT, sk1, b1, x2, flag);

    // ---- layer 2 (pool-collapsed, wbuf-free) ----
    gemm_bt2<<<dim3(16, 32, 1), 256, 0, stream>>>(x2, W2t, W2t, p2, p2, 4096, 2048, 2048);
    compute_sw<<<dim3(32, 256), 256, 0, stream>>>(p2, a_src2, a_tgt2, ss, st, flag);
    lpass_k<<<512, 256, 0, stream>>>(ss, st, mask, invl, flag);
    colsum2_k<<<dim3(32, 4, 4), 256, 0, stream>>>(ss, st, mask, invl, cbuf, flag);
    rowsum_k<<<dim3(4, 8, 4), 256, 0, stream>>>(x2, xbar);
    attn2_vec<<<dim3(32, 8), 256, 0, stream>>>(p2, cbuf, gA);
    skipvec_k<<<dim3(4, 8, 8), 256, 0, stream>>>(skip2, xbar, gS, flag);

    // ---- classify ----
    classify2_k<<<4, 256, 0, stream>>>(gA, gS, b2v, Wc, bc, d_out, flag);
}

// Round 7
// 451.420 us; speedup vs baseline: 2.5240x; 1.0046x over previous
//
#include <hip/hip_runtime.h>
#include <hip/hip_bf16.h>
#include <stdint.h>
#include <stddef.h>

typedef __hip_bfloat16 bf16;
typedef __attribute__((ext_vector_type(8))) short bhalf8;
typedef __attribute__((ext_vector_type(4))) float floatx4;

static __device__ __forceinline__ float b2f(bf16 v) { return __bfloat162float(v); }
static __device__ __forceinline__ bf16  f2b(float v) { return __float2bfloat16(v); }
static __device__ __forceinline__ short f2s(float v) {
    union { bf16 b; short s; } u; u.b = __float2bfloat16(v); return u.s;
}

// dtype-agnostic scalar load: flag==1 -> fp32 data, flag==0 -> bf16 data
static __device__ __forceinline__ float loadf(const void* p, size_t i, int f32) {
    return f32 ? ((const float*)p)[i] : b2f(((const bf16*)p)[i]);
}

// async global->LDS, 16B per lane. LDS dest must be wave-uniform base + lane*16.
static __device__ __forceinline__ void gl_lds16(const void* g, void* l) {
    __builtin_amdgcn_global_load_lds(
        (const __attribute__((address_space(1))) void*)g,
        (__attribute__((address_space(3))) void*)l, 16, 0, 0);
}

// load 16 consecutive mask values starting at 16-aligned index
static __device__ __forceinline__ void load_mask16(const void* mask, size_t idx,
                                                   int f32, float* mv) {
    if (f32) {
        const float4* p = (const float4*)((const float*)mask + idx);
        #pragma unroll
        for (int q = 0; q < 4; q++) {
            float4 v = p[q];
            mv[q * 4 + 0] = v.x; mv[q * 4 + 1] = v.y;
            mv[q * 4 + 2] = v.z; mv[q * 4 + 3] = v.w;
        }
    } else {
        const bf16* p = (const bf16*)mask + idx;
        #pragma unroll
        for (int t = 0; t < 16; t++) mv[t] = b2f(p[t]);
    }
}

// -------------------------------------------------------------------------
__global__ void detect_k(const void* w1raw, int* flag)
{
    if (threadIdx.x == 0 && blockIdx.x == 0) {
        const unsigned short* s = (const unsigned short*)w1raw;
        int bad = 0;
        for (int i = 0; i < 256; i++) {
            int e = (s[i] >> 7) & 0xFF;
            if (e > 0x85 || (e != 0 && e < 0x60)) bad++;
        }
        *flag = (bad > 16) ? 1 : 0;
    }
}

__global__ __launch_bounds__(256) void cvt_k(const void* __restrict__ src,
                                             bf16* __restrict__ dst, int n,
                                             const int* __restrict__ flag)
{
    const int f = *flag;
    int i = blockIdx.x * 256 + threadIdx.x;
    if (i < n) dst[i] = f ? f2b(((const float*)src)[i]) : ((const bf16*)src)[i];
}

// -------------------------------------------------------------------------
__global__ __launch_bounds__(256) void transpose_k(const void* __restrict__ in,
                                                   bf16* __restrict__ out,
                                                   int R, int C,
                                                   const int* __restrict__ flag)
{
    __shared__ bf16 tile[32][33];
    const int f = *flag;
    const int tx = threadIdx.x & 31;
    const int ty = threadIdx.x >> 5;
    const int c0 = blockIdx.x * 32;
    const int r0 = blockIdx.y * 32;
    #pragma unroll
    for (int yy = ty; yy < 32; yy += 8)
        tile[yy][tx] = f2b(loadf(in, (size_t)(r0 + yy) * C + c0 + tx, f));
    __syncthreads();
    #pragma unroll
    for (int yy = ty; yy < 32; yy += 8)
        out[(size_t)(c0 + yy) * R + r0 + tx] = tile[tx][yy];
}

// batched bf16 transpose: per b, in (1024 x 2048) -> out (2048 x 1024)
__global__ __launch_bounds__(256) void transpose_p(const bf16* __restrict__ in,
                                                   bf16* __restrict__ out)
{
    __shared__ bf16 tile[32][33];
    const int bz = blockIdx.z;
    const int tx = threadIdx.x & 31;
    const int ty = threadIdx.x >> 5;
    const int c0 = blockIdx.x * 32;
    const int r0 = blockIdx.y * 32;
    const bf16* ib = in + (size_t)bz * 1024 * 2048;
    bf16* ob = out + (size_t)bz * 1024 * 2048;
    #pragma unroll
    for (int yy = ty; yy < 32; yy += 8)
        tile[yy][tx] = ib[(size_t)(r0 + yy) * 2048 + c0 + tx];
    __syncthreads();
    #pragma unroll
    for (int yy = ty; yy < 32; yy += 8)
        ob[(size_t)(c0 + yy) * 1024 + r0 + tx] = tile[tx][yy];
}

// -------------------------------------------------------------------------
// Paired GEMM (layer 1 only now): C = A@B[z]. m97 structure.
__global__ __launch_bounds__(256) void gemm_bt2(const bf16* __restrict__ A,
                                                const bf16* __restrict__ Bt0,
                                                const bf16* __restrict__ Bt1,
                                                bf16* __restrict__ C0,
                                                bf16* __restrict__ C1,
                                                int M, int N, int K)
{
    __shared__ __align__(16) short sA[128][32];
    __shared__ __align__(16) short sB[128][32];
    const int tid  = threadIdx.x;
    const int bx   = blockIdx.x, by = blockIdx.y;
    const bf16* Bt = blockIdx.z ? Bt1 : Bt0;
    bf16* C        = blockIdx.z ? C1  : C0;
    const int wave = tid >> 6, lane = tid & 63;
    const int wm   = wave >> 1, wn = wave & 1;
    const int lrow = lane & 15, quad = lane >> 4;

    floatx4 acc[4][4];
    #pragma unroll
    for (int i = 0; i < 4; i++)
        #pragma unroll
        for (int j = 0; j < 4; j++)
            acc[i][j] = (floatx4){0.f, 0.f, 0.f, 0.f};

    const int srow = wave * 32 + (lane >> 2);
    const int scol = (lane & 3) * 8;
    const bf16* gA0 = A  + (size_t)(by * 128 + srow) * K + scol;
    const bf16* gA1 = gA0 + (size_t)16 * K;
    const bf16* gB0 = Bt + (size_t)(bx * 128 + srow) * K + scol;
    const bf16* gB1 = gB0 + (size_t)16 * K;
    char* lA0 = (char*)&sA[0][0] + wave * 2048 + lane * 16;
    char* lA1 = lA0 + 1024;
    char* lB0 = (char*)&sB[0][0] + wave * 2048 + lane * 16;
    char* lB1 = lB0 + 1024;

    for (int k0 = 0; k0 < K; k0 += 32) {
        __syncthreads();
        gl_lds16(gA0 + k0, lA0);
        gl_lds16(gA1 + k0, lA1);
        gl_lds16(gB0 + k0, lB0);
        gl_lds16(gB1 + k0, lB1);
        __syncthreads();
        bhalf8 af[4], bfr[4];
        #pragma unroll
        for (int t = 0; t < 4; t++) af[t]  = *(const bhalf8*)&sA[wm * 64 + t * 16 + lrow][quad * 8];
        #pragma unroll
        for (int t = 0; t < 4; t++) bfr[t] = *(const bhalf8*)&sB[wn * 64 + t * 16 + lrow][quad * 8];
        #pragma unroll
        for (int tm = 0; tm < 4; tm++)
            #pragma unroll
            for (int tn = 0; tn < 4; tn++)
                acc[tm][tn] = __builtin_amdgcn_mfma_f32_16x16x32_bf16(af[tm], bfr[tn], acc[tm][tn], 0, 0, 0);
    }

    #pragma unroll
    for (int tm = 0; tm < 4; tm++) {
        #pragma unroll
        for (int tn = 0; tn < 4; tn++) {
            const int col = bx * 128 + wn * 64 + tn * 16 + lrow;
            #pragma unroll
            for (int r = 0; r < 4; r++) {
                const int row = by * 128 + wm * 64 + tm * 16 + quad * 4 + r;
                C[(size_t)row * N + col] = f2b(acc[tm][tn][r]);
            }
        }
    }
}

// -------------------------------------------------------------------------
// s_src/s_tgt for layer 1: wave-autonomous dot over f=256.
__global__ __launch_bounds__(256) void compute_sw(const bf16* __restrict__ p,
                                                  const void* __restrict__ a_src,
                                                  const void* __restrict__ a_tgt,
                                                  float* __restrict__ s_src_t,
                                                  float* __restrict__ s_tgt_t,
                                                  const int* __restrict__ flag)
{
    const int f32 = *flag;
    const int bh = blockIdx.x, b = bh >> 3, h = bh & 7;
    const int wave = threadIdx.x >> 6, lane = threadIdx.x & 63;
    const int n = blockIdx.y * 4 + wave;
    const bf16* pr = p + ((size_t)(b * 1024 + n)) * 2048 + h * 256;
    float ss = 0.f, st = 0.f;
    #pragma unroll
    for (int q = 0; q < 4; q++) {
        const int f = q * 64 + lane;
        float pv = b2f(pr[f]);
        ss = fmaf(pv, loadf(a_src, h * 256 + f, f32), ss);
        st = fmaf(pv, loadf(a_tgt, h * 256 + f, f32), st);
    }
    #pragma unroll
    for (int off = 32; off; off >>= 1) {
        ss += __shfl_down(ss, off, 64);
        st += __shfl_down(st, off, 64);
    }
    if (lane == 0) {
        s_src_t[bh * 1024 + n] = ss;
        s_tgt_t[bh * 1024 + n] = st;
    }
}

// -------------------------------------------------------------------------
// Fused layer-1 attention, DOUBLE-BUFFERED: exp-tile k+1 generated + B-tile
// k+1 prefetched while MFMA consumes tile k. One barrier per K-iter.
__global__ __launch_bounds__(256) void attn_fused(const float* __restrict__ s_src_t,
                                                  const float* __restrict__ s_tgt_t,
                                                  const void* __restrict__ mask,
                                                  const bf16* __restrict__ pT,
                                                  const bf16* __restrict__ sk,
                                                  const void* __restrict__ bias,
                                                  bf16* __restrict__ x2,
                                                  const int* __restrict__ flag)
{
    __shared__ __align__(16) short sA[2][128][32];
    __shared__ __align__(16) short sB[2][128][32];
    __shared__ float sStgt[1024];
    __shared__ float sInvl[128];

    const int tid = threadIdx.x;
    const int bx = blockIdx.x, by = blockIdx.y, bh = blockIdx.z;
    const int b = bh >> 3, h = bh & 7;
    const int f32 = *flag;
    const int wave = tid >> 6, lane = tid & 63;
    const int wm = wave >> 1, wn = wave & 1;
    const int lrow = lane & 15, quad = lane >> 4;

    #pragma unroll
    for (int q = 0; q < 4; q++)
        sStgt[q * 256 + tid] = s_tgt_t[bh * 1024 + q * 256 + tid];

    // score-gen assignment: 2 threads per row
    const int irow = tid >> 1;                 // 0..127
    const int jh16 = (tid & 1) * 16;           // 0 or 16
    const float ssr = s_src_t[bh * 1024 + by * 128 + irow];
    const size_t mrow0 = ((size_t)(b * 1024 + by * 128 + irow)) << 10;

    // B staging (global_load_lds)
    const int srow = wave * 32 + (lane >> 2);
    const int scol = (lane & 3) * 8;
    const bf16* gB0 = pT + ((size_t)bh << 18) + (size_t)(bx * 128 + srow) * 1024 + scol;
    const bf16* gB1 = gB0 + (size_t)16 * 1024;
    char* lBbase = (char*)&sB[0][0][0] + wave * 2048 + lane * 16;

    floatx4 acc[4][4];
    #pragma unroll
    for (int i = 0; i < 4; i++)
        #pragma unroll
        for (int j = 0; j < 4; j++)
            acc[i][j] = (floatx4){0.f, 0.f, 0.f, 0.f};

    float lacc = 0.f;

    __syncthreads();   // sStgt visible

    // ---- prologue: tile 0 ----
    gl_lds16(gB0, lBbase);
    gl_lds16(gB1, lBbase + 1024);
    {
        float mv[16];
        load_mask16(mask, mrow0 + jh16, f32, mv);
        short ev[16];
        #pragma unroll
        for (int t = 0; t < 16; t++) {
            float x = ssr + sStgt[jh16 + t];
            x = (x > 0.f) ? x : 0.2f * x;
            float e = __expf(x + mv[t]);
            lacc += e;
            ev[t] = f2s(e);
        }
        *(int4*)&sA[0][irow][jh16]     = *(int4*)&ev[0];
        *(int4*)&sA[0][irow][jh16 + 8] = *(int4*)&ev[8];
    }

    int cur = 0;
    for (int k0 = 0; k0 < 1024; k0 += 32, cur ^= 1) {
        __syncthreads();   // tile[cur] ready; tile[cur^1] fully consumed
        if (k0 + 32 < 1024) {
            const int nxt = cur ^ 1;
            gl_lds16(gB0 + (k0 + 32), lBbase + nxt * 8192);
            gl_lds16(gB1 + (k0 + 32), lBbase + nxt * 8192 + 1024);
            float mv[16];
            load_mask16(mask, mrow0 + k0 + 32 + jh16, f32, mv);
            short ev[16];
            #pragma unroll
            for (int t = 0; t < 16; t++) {
                float x = ssr + sStgt[k0 + 32 + jh16 + t];
                x = (x > 0.f) ? x : 0.2f * x;
                float e = __expf(x + mv[t]);
                lacc += e;
                ev[t] = f2s(e);
            }
            *(int4*)&sA[nxt][irow][jh16]     = *(int4*)&ev[0];
            *(int4*)&sA[nxt][irow][jh16 + 8] = *(int4*)&ev[8];
        }
        bhalf8 af[4], bfr[4];
        #pragma unroll
        for (int t = 0; t < 4; t++) af[t]  = *(const bhalf8*)&sA[cur][wm * 64 + t * 16 + lrow][quad * 8];
        #pragma unroll
        for (int t = 0; t < 4; t++) bfr[t] = *(const bhalf8*)&sB[cur][wn * 64 + t * 16 + lrow][quad * 8];
        #pragma unroll
        for (int tm = 0; tm < 4; tm++)
            #pragma unroll
            for (int tn = 0; tn < 4; tn++)
                acc[tm][tn] = __builtin_amdgcn_mfma_f32_16x16x32_bf16(af[tm], bfr[tn], acc[tm][tn], 0, 0, 0);
    }

    // row denominators: pair threads share a row (lane^1)
    lacc += __shfl_xor(lacc, 1, 64);
    if ((tid & 1) == 0) sInvl[irow] = 1.0f / lacc;
    __syncthreads();

    #pragma unroll
    for (int tm = 0; tm < 4; tm++) {
        #pragma unroll
        for (int r = 0; r < 4; r++) {
            const int rl = wm * 64 + tm * 16 + quad * 4 + r;
            const int row = by * 128 + rl;
            const float il = sInvl[rl];
            #pragma unroll
            for (int tn = 0; tn < 4; tn++) {
                const int col = bx * 128 + wn * 64 + tn * 16 + lrow;
                const int hf = h * 256 + col;
                const size_t idx = ((size_t)(b * 1024 + row)) * 2048 + hf;
                float v = acc[tm][tn][r] * il + b2f(sk[idx]) + loadf(bias, hf, f32);
                v = (v > 0.f) ? v : expm1f(v);     // ELU
                x2[idx] = f2b(v);
            }
        }
    }
}

// -------------------------------------------------------------------------
// Wa[hh][k] = sum_f W2[k, h*256+f] * a[h][f], hh 0..7 = a_src2, 8..15 = a_tgt2.
__global__ __launch_bounds__(256) void wproj_k(const void* __restrict__ W2,
                                               const void* __restrict__ a_src2,
                                               const void* __restrict__ a_tgt2,
                                               float* __restrict__ Wa,
                                               const int* __restrict__ flag)
{
    __shared__ float sa[256];
    const int f32 = *flag;
    const int id = blockIdx.x * 256 + threadIdx.x;   // 0..32767
    const int hh = id >> 11, k = id & 2047, h = hh & 7;
    const void* a = (hh < 8) ? a_src2 : a_tgt2;
    sa[threadIdx.x] = loadf(a, h * 256 + threadIdx.x, f32);
    __syncthreads();
    float acc = 0.f;
    #pragma unroll 4
    for (int f = 0; f < 256; f++)
        acc = fmaf(loadf(W2, (size_t)k * 2048 + h * 256 + f, f32), sa[f], acc);
    Wa[hh * 2048 + k] = acc;
}

// -------------------------------------------------------------------------
// Layer-2 scores: ss/st[bh][n] = sum_k x2[b,n,k] * Wa[hh][k]. Block per node.
__global__ __launch_bounds__(256) void score2_k(const bf16* __restrict__ x2,
                                                const float* __restrict__ Wa,
                                                float* __restrict__ s_src_t,
                                                float* __restrict__ s_tgt_t)
{
    const int bid = blockIdx.x;           // b*1024 + n
    const int b = bid >> 10, n = bid & 1023;
    const int wave = threadIdx.x >> 6, lane = threadIdx.x & 63;
    const bf16* xr = x2 + (size_t)bid * 2048;
    float xv[32];
    #pragma unroll
    for (int q = 0; q < 32; q++) xv[q] = b2f(xr[q * 64 + lane]);
    #pragma unroll
    for (int c = 0; c < 4; c++) {
        const int hh = c * 4 + wave;      // 0..15
        const float* wr = Wa + hh * 2048;
        float acc = 0.f;
        #pragma unroll
        for (int q = 0; q < 32; q++) acc = fmaf(xv[q], wr[q * 64 + lane], acc);
        #pragma unroll
        for (int off = 32; off; off >>= 1) acc += __shfl_down(acc, off, 64);
        if (lane == 0) {
            if (hh < 8) s_src_t[(b * 8 + hh) * 1024 + n] = acc;
            else        s_tgt_t[(b * 8 + hh - 8) * 1024 + n] = acc;
        }
    }
}

// -------------------------------------------------------------------------
// Layer-2 denominators. Wave handles h=wave, wave+4.
__global__ __launch_bounds__(256) void lpass_k(const float* __restrict__ s_src_t,
                                               const float* __restrict__ s_tgt_t,
                                               const void* __restrict__ mask,
                                               float* __restrict__ invl,
                                               const int* __restrict__ flag)
{
    const int f32 = *flag;
    const int b = blockIdx.x >> 7, itile = blockIdx.x & 127;
    const int wave = threadIdx.x >> 6, lane = threadIdx.x & 63;
    const int h0 = wave, h1 = wave + 4;
    float st0[16], st1[16];
    #pragma unroll
    for (int q = 0; q < 16; q++) {
        st0[q] = s_tgt_t[(b * 8 + h0) * 1024 + q * 64 + lane];
        st1[q] = s_tgt_t[(b * 8 + h1) * 1024 + q * 64 + lane];
    }
    for (int r = 0; r < 8; r++) {
        const int i = itile * 8 + r;
        const size_t moff = ((size_t)b * 1024 + i) * 1024;
        float mrow[16];
        #pragma unroll
        for (int q = 0; q < 16; q++) mrow[q] = loadf(mask, moff + q * 64 + lane, f32);
        #pragma unroll
        for (int hh = 0; hh < 2; hh++) {
            const int h = hh ? h1 : h0;
            const float ssr = s_src_t[(b * 8 + h) * 1024 + i];
            float l = 0.f;
            #pragma unroll
            for (int q = 0; q < 16; q++) {
                float x = ssr + (hh ? st1[q] : st0[q]);
                x = (x > 0.f) ? x : 0.2f * x;
                l += __expf(x + mrow[q]);
            }
            #pragma unroll
            for (int off = 32; off; off >>= 1) l += __shfl_down(l, off, 64);
            if (lane == 0) invl[(b * 8 + h) * 1024 + i] = 1.0f / l;
        }
    }
}

// -------------------------------------------------------------------------
// c[bh][j] += sum_{i in chunk} invl[i]*e[i,j], e regenerated inline.
__global__ __launch_bounds__(256) void colsum2_k(const float* __restrict__ s_src_t,
                                                 const float* __restrict__ s_tgt_t,
                                                 const void* __restrict__ mask,
                                                 const float* __restrict__ invl,
                                                 float* __restrict__ c,
                                                 const int* __restrict__ flag)
{
    __shared__ float sS[256], sIl[256];
    const int f32 = *flag;
    const int bh = blockIdx.x, b = bh >> 3;
    const int j = blockIdx.y * 256 + threadIdx.x;
    const int i0 = blockIdx.z * 256;
    sS[threadIdx.x]  = s_src_t[bh * 1024 + i0 + threadIdx.x];
    sIl[threadIdx.x] = invl[bh * 1024 + i0 + threadIdx.x];
    __syncthreads();
    const float stj = s_tgt_t[bh * 1024 + j];
    float acc = 0.f;
    #pragma unroll 4
    for (int ii = 0; ii < 256; ii++) {
        float x = sS[ii] + stj;
        x = (x > 0.f) ? x : 0.2f * x;
        float e = __expf(x + loadf(mask, (((size_t)(b * 1024 + i0 + ii)) << 10) + j, f32));
        acc = fmaf(sIl[ii], e, acc);
    }
    atomicAdd(&c[bh * 1024 + j], acc);
}

// -------------------------------------------------------------------------
__global__ void zero_f(float* __restrict__ p, int n)
{
    int idx = blockIdx.x * blockDim.x + threadIdx.x;
    if (idx < n) p[idx] = 0.f;
}

// y[bh][k] += sum_{j in chunk} c[bh,j]*x2[b,j,k]; xbar[b][k] += sum_j x2[b,j,k]
__global__ __launch_bounds__(256) void yx_k(const bf16* __restrict__ x2,
                                            const float* __restrict__ c,
                                            float* __restrict__ y,
                                            float* __restrict__ xbar)
{
    __shared__ float sC[8][128];
    const int b = blockIdx.x, kt = blockIdx.y, jc = blockIdx.z;
    const int t = threadIdx.x;
    const int k = kt * 256 + t;
    const int j0 = jc * 128;
    for (int idx = t; idx < 8 * 128; idx += 256) {
        const int h = idx >> 7, jj = idx & 127;
        sC[h][jj] = c[(b * 8 + h) * 1024 + j0 + jj];
    }
    __syncthreads();
    float acc[8] = {0.f, 0.f, 0.f, 0.f, 0.f, 0.f, 0.f, 0.f};
    float ax = 0.f;
    for (int jj = 0; jj < 128; jj++) {
        const float xv = b2f(x2[((size_t)(b * 1024 + j0 + jj)) * 2048 + k]);
        ax += xv;
        #pragma unroll
        for (int h = 0; h < 8; h++) acc[h] = fmaf(sC[h][jj], xv, acc[h]);
    }
    #pragma unroll
    for (int h = 0; h < 8; h++)
        atomicAdd(&y[(b * 8 + h) * 2048 + k], acc[h]);
    atomicAdd(&xbar[b * 2048 + k], ax);
}

// gA[bh][f] += sum_{k in chunk} y[bh,k] * W2[k, h*256+f]
__global__ __launch_bounds__(256) void gamat_k(const void* __restrict__ W2,
                                               const float* __restrict__ y,
                                               float* __restrict__ gA,
                                               const int* __restrict__ flag)
{
    __shared__ float sY[256];
    const int f32 = *flag;
    const int bh = blockIdx.x, kc = blockIdx.y;
    const int h = bh & 7, f = threadIdx.x;
    const int k0 = kc * 256;
    sY[threadIdx.x] = y[bh * 2048 + k0 + threadIdx.x];
    __syncthreads();
    float acc = 0.f;
    #pragma unroll 4
    for (int kk = 0; kk < 256; kk++)
        acc = fmaf(sY[kk], loadf(W2, (size_t)(k0 + kk) * 2048 + h * 256 + f, f32), acc);
    atomicAdd(&gA[bh * 256 + f], acc);
}

// gS[b][hf] += sum_{k in chunk} xbar[b,k] * skip2[k,hf]
__global__ __launch_bounds__(256) void skipvec_k(const void* __restrict__ skip2,
                                                 const float* __restrict__ xbar,
                                                 float* __restrict__ gS,
                                                 const int* __restrict__ flag)
{
    const int f32 = *flag;
    const int b = blockIdx.x, hft = blockIdx.y, kc = blockIdx.z;
    const int hf = hft * 256 + threadIdx.x;
    float acc = 0.f;
    #pragma unroll 4
    for (int kk = 0; kk < 256; kk++) {
        const int k = kc * 256 + kk;
        acc = fmaf(xbar[b * 2048 + k], loadf(skip2, (size_t)k * 2048 + hf, f32), acc);
    }
    atomicAdd(&gS[b * 2048 + hf], acc);
}

// g[b,f] = (sum_h gA + sum_h gS)/(8*1024) + b2[f]; out = g@Wc + bc
__global__ __launch_bounds__(256) void classify2_k(const float* __restrict__ gA,
                                                   const float* __restrict__ gS,
                                                   const void* __restrict__ b2,
                                                   const void* __restrict__ Wc,
                                                   const void* __restrict__ bc,
                                                   void* __restrict__ out,
                                                   const int* __restrict__ flag)
{
    __shared__ float gv[256];
    const int f32 = *flag;
    const int b = blockIdx.x, f = threadIdx.x;
    float s = 0.f;
    #pragma unroll
    for (int h = 0; h < 8; h++)
        s += gA[(b * 8 + h) * 256 + f] + gS[b * 2048 + h * 256 + f];
    gv[f] = s * (1.0f / 8192.0f) + loadf(b2, f, f32);
    __syncthreads();
    if (f < 10) {
        float acc = loadf(bc, f, f32);
        for (int k = 0; k < 256; k++)
            acc = fmaf(gv[k], loadf(Wc, k * 10 + f, f32), acc);
        if (f32) ((float*)out)[b * 10 + f] = acc;
        else     ((bf16*)out)[b * 10 + f] = f2b(acc);
    }
}

// -------------------------------------------------------------------------
extern "C" void kernel_launch(void* const* d_in, const int* in_sizes, int n_in,
                              void* d_out, int out_size, void* d_ws, size_t ws_size,
                              hipStream_t stream)
{
    (void)in_sizes; (void)n_in; (void)out_size; (void)ws_size;
    const void* feat   = d_in[0];
    const void* mask   = d_in[2];
    const void* W1     = d_in[3];
    const void* a_src1 = d_in[4];
    const void* a_tgt1 = d_in[5];
    const void* skip1  = d_in[6];
    const void* b1     = d_in[7];
    const void* W2     = d_in[8];
    const void* a_src2 = d_in[9];
    const void* a_tgt2 = d_in[10];
    const void* skip2  = d_in[11];
    const void* b2v    = d_in[12];
    const void* Wc     = d_in[13];
    const void* bc     = d_in[14];

    char* ws = (char*)d_ws;
    size_t off = 0;
    auto alloc = [&](size_t bytes) -> void* {
        void* p = ws + off;
        off += (bytes + 255) & ~(size_t)255;
        return p;
    };
    int*   flag = (int*)alloc(256);
    bf16*  featc= (bf16*)alloc(4096ull * 256 * 2);
    bf16*  W1t  = (bf16*)alloc(2048ull * 256 * 2);
    bf16*  S1t  = (bf16*)alloc(2048ull * 256 * 2);
    bf16*  p1   = (bf16*)alloc(4096ull * 2048 * 2);
    bf16*  sk1  = (bf16*)alloc(4096ull * 2048 * 2);
    bf16*  x2   = (bf16*)alloc(4096ull * 2048 * 2);
    bf16*  pT   = (bf16*)alloc(4096ull * 2048 * 2);
    float* invl = (float*)alloc(32ull * 1024 * 4);
    float* ss   = (float*)alloc(32ull * 1024 * 4);
    float* st   = (float*)alloc(32ull * 1024 * 4);
    float* Wa   = (float*)alloc(16ull * 2048 * 4);
    // cbuf, gA, gS, xbar, y contiguous: one zero_f covers all
    float* cbuf = (float*)alloc(32ull * 1024 * 4);     // 32768 floats
    float* gA   = (float*)alloc(32ull * 256 * 4);      // 8192
    float* gS   = (float*)alloc(4ull * 2048 * 4);      // 8192
    float* xbar = (float*)alloc(4ull * 2048 * 4);      // 8192
    float* y    = (float*)alloc(32ull * 2048 * 4);     // 65536

    detect_k<<<1, 64, 0, stream>>>(W1, flag);
    cvt_k<<<4096, 256, 0, stream>>>(feat, featc, 4096 * 256, flag);
    zero_f<<<480, 256, 0, stream>>>(cbuf, 32768 + 3 * 8192 + 65536);

    transpose_k<<<dim3(64, 8), 256, 0, stream>>>(W1,    W1t, 256, 2048, flag);
    transpose_k<<<dim3(64, 8), 256, 0, stream>>>(skip1, S1t, 256, 2048, flag);
    wproj_k<<<128, 256, 0, stream>>>(W2, a_src2, a_tgt2, Wa, flag);

    // ---- layer 1 ----
    gemm_bt2<<<dim3(16, 32, 2), 256, 0, stream>>>(featc, W1t, S1t, p1, sk1, 4096, 2048, 256);
    transpose_p<<<dim3(64, 32, 4), 256, 0, stream>>>(p1, pT);
    compute_sw<<<dim3(32, 256), 256, 0, stream>>>(p1, a_src1, a_tgt1, ss, st, flag);
    attn_fused<<<dim3(2, 8, 32), 256, 0, stream>>>(ss, st, mask, pT, sk1, b1, x2, flag);

    // ---- layer 2 (fully collapsed: no dense GEMM) ----
    score2_k<<<4096, 256, 0, stream>>>(x2, Wa, ss, st);
    lpass_k<<<512, 256, 0, stream>>>(ss, st, mask, invl, flag);
    colsum2_k<<<dim3(32, 4, 4), 256, 0, stream>>>(ss, st, mask, invl, cbuf, flag);
    yx_k<<<dim3(4, 8, 8), 256, 0, stream>>>(x2, cbuf, y, xbar);
    gamat_k<<<dim3(32, 8), 256, 0, stream>>>(W2, y, gA, flag);
    skipvec_k<<<dim3(4, 8, 8), 256, 0, stream>>>(skip2, xbar, gS, flag);

    // ---- classify ----
    classify2_k<<<4, 256, 0, stream>>>(gA, gS, b2v, Wc, bc, d_out, flag);
}